// Round 1
// baseline (667.319 us; speedup 1.0000x reference)
//
#include <hip/hip_runtime.h>
#include <hip/hip_bf16.h>
#include <stdint.h>

#define BDIM 256
#define B_   8
#define NCLS 80
#define G_   100
#define N_   33600
#define TOPK_ 13

// ---------- helpers ----------

__device__ __forceinline__ unsigned int fkey(float f){
  unsigned int u = __float_as_uint(f);
  return (u & 0x80000000u) ? ~u : (u | 0x80000000u);  // monotonic float->uint
}

__device__ __forceinline__ float iou_pair(float4 pb, float pa, float4 gb, float ga){
  #pragma clang fp contract(off)
  float lx = fmaxf(pb.x, gb.x), ly = fmaxf(pb.y, gb.y);
  float rx = fminf(pb.z, gb.z), ry = fminf(pb.w, gb.w);
  float w = fmaxf(rx - lx, 0.0f), h = fmaxf(ry - ly, 0.0f);
  float ov = w * h;
  float un = pa + ga - ov;
  return ov / fmaxf(un, 1e-6f);
}

// cost = bce*(scale^2) + (-log(iou+eps)*3) + 10^(dist-3); INF-masked by valid
__device__ __forceinline__ float cost_eval(float iou, float x, float dist, bool valid){
  #pragma clang fp contract(off)
  float prior = exp2f((dist - 3.0f) * 3.321928094887362f);   // 10^(dist-3)
  float iouc  = -logf(iou + 1e-7f) * 3.0f;
  float sig   = 1.0f / (1.0f + expf(-x));
  float sc    = iou - sig;
  float bce   = fmaxf(x, 0.0f) + log1pf(expf(-fabsf(x))) - x * iou;
  float c     = bce * (sc * sc) + iouc + prior;
  return valid ? c : 1e8f;
}

// ---------- kernel 0: valid mask (anchor strictly inside any valid gt) + zero bitmask ----------

__global__ void __launch_bounds__(BDIM) k_validmask(
    const float* __restrict__ priors,
    const float* __restrict__ gt_bboxes,
    const float* __restrict__ pad_flag,
    unsigned char* __restrict__ valid_mask,
    uint32_t* __restrict__ match_mask)
{
  int b = blockIdx.y;
  __shared__ float4 sbox[G_];
  __shared__ float  sflag[G_];
  for (int g = threadIdx.x; g < G_; g += BDIM){
    sbox[g]  = ((const float4*)gt_bboxes)[b*G_ + g];
    sflag[g] = pad_flag[b*G_ + g];
  }
  __syncthreads();
  int n = blockIdx.x*BDIM + threadIdx.x;
  if (n >= N_) return;
  float cx = priors[n*4+0], cy = priors[n*4+1];
  bool v = false;
  for (int g = 0; g < G_; ++g){
    float4 gb = sbox[g];
    bool in = (cx - gb.x > 0.0f) & (cy - gb.y > 0.0f) &
              (gb.z - cx > 0.0f) & (gb.w - cy > 0.0f) & (sflag[g] > 0.0f);
    v |= in;
  }
  size_t idx = (size_t)b*N_ + n;
  valid_mask[idx] = v ? 1 : 0;
  ((uint4*)match_mask)[idx] = make_uint4(0u,0u,0u,0u);
}

// ---------- kernel 1: per (b,g) top-13 cost candidates + dyn_k, scatter match bits ----------

__global__ void __launch_bounds__(BDIM) k_topk(
    const float* __restrict__ pred_bboxes,
    const float* __restrict__ pred_scores,
    const float* __restrict__ priors,
    const int*   __restrict__ gt_labels,
    const float* __restrict__ gt_bboxes,
    const float* __restrict__ pad_flag,
    const unsigned char* __restrict__ valid_mask,
    uint32_t* __restrict__ match_mask)
{
  #pragma clang fp contract(off)
  int g = blockIdx.x, b = blockIdx.y;
  if (pad_flag[b*G_ + g] <= 0.0f) return;   // invalid gt: contributes no matches

  float4 gb = ((const float4*)gt_bboxes)[b*G_ + g];
  float ga  = (gb.z - gb.x) * (gb.w - gb.y);
  float gcx = (gb.x + gb.z) * 0.5f, gcy = (gb.y + gb.w) * 0.5f;
  int   lbl = gt_labels[b*G_ + g];
  int   tid = threadIdx.x;

  unsigned long long ck[TOPK_];  // smallest 13 (cost,idx) keys, ascending
  float ti[TOPK_];               // largest 13 ious, descending
  #pragma unroll
  for (int j = 0; j < TOPK_; ++j){ ck[j] = ~0ull; ti[j] = -1.0f; }

  for (int n = tid; n < N_; n += BDIM){
    size_t idx = (size_t)b*N_ + n;
    float4 pb = ((const float4*)pred_bboxes)[idx];
    float pa  = (pb.z - pb.x) * (pb.w - pb.y);
    float iou = iou_pair(pb, pa, gb, ga);

    if (iou > ti[TOPK_-1]){                     // insert into descending list
      float nt[TOPK_];
      #pragma unroll
      for (int j = 0; j < TOPK_; ++j){
        float prev = (j == 0) ? 0.0f : ti[j-1];
        nt[j] = (iou <= ti[j]) ? ti[j] : ((j == 0 || iou <= prev) ? iou : prev);
      }
      #pragma unroll
      for (int j = 0; j < TOPK_; ++j) ti[j] = nt[j];
    }

    float4 pr = ((const float4*)priors)[n];
    bool valid = valid_mask[idx] != 0;
    float dx = pr.x - gcx, dy = pr.y - gcy;
    float dist = sqrtf(dx*dx + dy*dy) / pr.z;
    float x = pred_scores[idx*(size_t)NCLS + lbl];
    float c = cost_eval(iou, x, dist, valid);
    unsigned long long key = ((unsigned long long)fkey(c) << 32) | (unsigned int)n;

    if (key < ck[TOPK_-1]){                     // insert into ascending list
      unsigned long long nk[TOPK_];
      #pragma unroll
      for (int j = 0; j < TOPK_; ++j){
        unsigned long long prev = (j == 0) ? 0ull : ck[j-1];
        nk[j] = (key >= ck[j]) ? ck[j] : ((j == 0 || key >= prev) ? key : prev);
      }
      #pragma unroll
      for (int j = 0; j < TOPK_; ++j) ck[j] = nk[j];
    }
  }

  // block tree-merge: cost keys
  __shared__ unsigned long long sk[BDIM][TOPK_];
  #pragma unroll
  for (int j = 0; j < TOPK_; ++j) sk[tid][j] = ck[j];
  for (int off = BDIM/2; off > 0; off >>= 1){
    __syncthreads();
    if (tid < off){
      unsigned long long m[TOPK_];
      int i1 = 0, i2 = 0;
      #pragma unroll
      for (int j = 0; j < TOPK_; ++j){
        unsigned long long a = sk[tid][i1], c2 = sk[tid+off][i2];
        if (a <= c2){ m[j] = a; ++i1; } else { m[j] = c2; ++i2; }
      }
      #pragma unroll
      for (int j = 0; j < TOPK_; ++j) sk[tid][j] = m[j];
    }
  }

  // block tree-merge: iou top-13 (descending)
  __shared__ float si[BDIM][TOPK_];
  #pragma unroll
  for (int j = 0; j < TOPK_; ++j) si[tid][j] = ti[j];
  for (int off = BDIM/2; off > 0; off >>= 1){
    __syncthreads();
    if (tid < off){
      float m[TOPK_];
      int i1 = 0, i2 = 0;
      #pragma unroll
      for (int j = 0; j < TOPK_; ++j){
        float a = si[tid][i1], c2 = si[tid+off][i2];
        if (a >= c2){ m[j] = a; ++i1; } else { m[j] = c2; ++i2; }
      }
      #pragma unroll
      for (int j = 0; j < TOPK_; ++j) si[tid][j] = m[j];
    }
  }
  __syncthreads();

  if (tid == 0){
    float s = 0.0f;
    #pragma unroll
    for (int j = 0; j < TOPK_; ++j) s += si[0][j];   // descending order sum (matches top_k output order)
    int dynk = (int)s;                                // trunc toward zero
    if (dynk < 1) dynk = 1;
    if (dynk > TOPK_) dynk = TOPK_;
    for (int j = 0; j < dynk; ++j){
      int n = (int)(sk[0][j] & 0xffffffffu);
      atomicOr(&match_mask[((size_t)b*N_ + n)*4 + (g >> 5)], 1u << (g & 31));
    }
  }
}

// ---------- kernel 2: per (b,n) final assignment ----------

__global__ void __launch_bounds__(BDIM) k_assign(
    const float* __restrict__ pred_bboxes,
    const float* __restrict__ pred_scores,
    const float* __restrict__ priors,
    const int*   __restrict__ gt_labels,
    const float* __restrict__ gt_bboxes,
    const unsigned char* __restrict__ valid_mask,
    const uint32_t* __restrict__ match_mask,
    float* __restrict__ out)
{
  #pragma clang fp contract(off)
  int b = blockIdx.y;
  __shared__ float4 sbox[G_];
  __shared__ int    slbl[G_];
  __shared__ float  sga[G_], sgcx[G_], sgcy[G_];
  for (int g = threadIdx.x; g < G_; g += BDIM){
    float4 gb = ((const float4*)gt_bboxes)[b*G_ + g];
    sbox[g] = gb;
    slbl[g] = gt_labels[b*G_ + g];
    sga[g]  = (gb.z - gb.x) * (gb.w - gb.y);
    sgcx[g] = (gb.x + gb.z) * 0.5f;
    sgcy[g] = (gb.y + gb.w) * 0.5f;
  }
  __syncthreads();
  int n = blockIdx.x*BDIM + threadIdx.x;
  if (n >= N_) return;

  size_t idx = (size_t)b*N_ + n;
  uint4 mm = ((const uint4*)match_mask)[idx];
  int count = __popc(mm.x) + __popc(mm.y) + __popc(mm.z) + __popc(mm.w);
  float4 pb = ((const float4*)pred_bboxes)[idx];
  float pa  = (pb.z - pb.x) * (pb.w - pb.y);
  float4 pr = ((const float4*)priors)[n];
  bool valid = valid_mask[idx] != 0;
  const float* srow = pred_scores + idx*(size_t)NCLS;

  float minc = 0.0f; int amin = 0; float iou_amin = 0.0f; float iou_sum = 0.0f;
  bool first = true;
  #pragma unroll
  for (int w = 0; w < 4; ++w){
    uint32_t word = (w == 0) ? mm.x : (w == 1) ? mm.y : (w == 2) ? mm.z : mm.w;
    const int glim = (w < 3) ? 32 : (G_ - 96);
    for (int g2 = 0; g2 < glim; ++g2){
      int g = w*32 + g2;
      float4 gb = sbox[g];
      float iou = iou_pair(pb, pa, gb, sga[g]);
      float dx = pr.x - sgcx[g], dy = pr.y - sgcy[g];
      float dist = sqrtf(dx*dx + dy*dy) / pr.z;
      float x = srow[slbl[g]];
      float c = cost_eval(iou, x, dist, valid);
      if (first || c < minc){ minc = c; amin = g; iou_amin = iou; first = false; }
      if ((word >> g2) & 1u) iou_sum += iou;
    }
  }

  bool multi = count > 1;
  int mg; float mi; bool fg;
  if (multi){ mg = amin; mi = iou_amin; fg = true; }       // onehot at argmin
  else {
    fg = count > 0;
    mg = mm.x ? (__ffs(mm.x) - 1) :
         mm.y ? (31 + __ffs(mm.y)) :
         mm.z ? (63 + __ffs(mm.z)) :
         mm.w ? (95 + __ffs(mm.w)) : 0;
    mi = iou_sum;                                           // <=1 term, exact
  }

  out[idx] = fg ? (float)slbl[mg] : (float)NCLS;           // assigned_labels
  out[(size_t)B_*N_ + idx] = 1.0f;                          // weights
  float4 ob = fg ? sbox[mg] : make_float4(0.f,0.f,0.f,0.f);
  ((float4*)(out + (size_t)2*B_*N_))[idx] = ob;             // assigned_bboxes
  out[(size_t)6*B_*N_ + idx] = fg ? mi : 0.0f;              // assign_metrics
}

// ---------- launch ----------

extern "C" void kernel_launch(void* const* d_in, const int* in_sizes, int n_in,
                              void* d_out, int out_size, void* d_ws, size_t ws_size,
                              hipStream_t stream) {
  const float* pred_bboxes = (const float*)d_in[0];
  const float* pred_scores = (const float*)d_in[1];
  const float* priors      = (const float*)d_in[2];
  const int*   gt_labels   = (const int*)  d_in[3];
  const float* gt_bboxes   = (const float*)d_in[4];
  const float* pad_flag    = (const float*)d_in[5];
  float* out = (float*)d_out;

  // ws layout: match bitmask (B*N*4 u32 = 4,300,800 B) then valid mask (B*N bytes)
  uint32_t* match_mask = (uint32_t*)d_ws;
  unsigned char* valid_mask = (unsigned char*)d_ws + (size_t)B_*N_*4*sizeof(uint32_t);

  dim3 gridN((N_ + BDIM - 1)/BDIM, B_);
  k_validmask<<<gridN, BDIM, 0, stream>>>(priors, gt_bboxes, pad_flag, valid_mask, match_mask);

  dim3 gridG(G_, B_);
  k_topk<<<gridG, BDIM, 0, stream>>>(pred_bboxes, pred_scores, priors, gt_labels,
                                     gt_bboxes, pad_flag, valid_mask, match_mask);

  k_assign<<<gridN, BDIM, 0, stream>>>(pred_bboxes, pred_scores, priors, gt_labels,
                                       gt_bboxes, valid_mask, match_mask, out);
}

// Round 2
// 495.279 us; speedup vs baseline: 1.3474x; 1.3474x over previous
//
#include <hip/hip_runtime.h>
#include <hip/hip_bf16.h>
#include <stdint.h>

#define BDIM 256
#define PDIM 128            // k_prep block size (128 rows staged in LDS)
#define B_   8
#define NCLS 80
#define G_   100
#define N_   33600
#define TOPK_ 13
#define LDS_STRIDE 81       // 81 mod 32 = 17, gcd(17,32)=1 -> conflict-free column reads

// ---------- helpers ----------

__device__ __forceinline__ unsigned int fkey(float f){
  unsigned int u = __float_as_uint(f);
  return (u & 0x80000000u) ? ~u : (u | 0x80000000u);  // monotonic float->uint
}

__device__ __forceinline__ float iou_pair(float4 pb, float pa, float4 gb, float ga){
  #pragma clang fp contract(off)
  float lx = fmaxf(pb.x, gb.x), ly = fmaxf(pb.y, gb.y);
  float rx = fminf(pb.z, gb.z), ry = fminf(pb.w, gb.w);
  float w = fmaxf(rx - lx, 0.0f), h = fmaxf(ry - ly, 0.0f);
  float ov = w * h;
  float un = pa + ga - ov;
  return ov / fmaxf(un, 1e-6f);
}

// cost = bce*(scale^2) + (-log(iou+eps)*3) + 10^(dist-3); INF-masked by valid
__device__ __forceinline__ float cost_eval(float iou, float x, float dist, bool valid){
  #pragma clang fp contract(off)
  float prior = exp2f((dist - 3.0f) * 3.321928094887362f);   // 10^(dist-3)
  float iouc  = -logf(iou + 1e-7f) * 3.0f;
  float sig   = 1.0f / (1.0f + expf(-x));
  float sc    = iou - sig;
  float bce   = fmaxf(x, 0.0f) + log1pf(expf(-fabsf(x))) - x * iou;
  float c     = bce * (sc * sc) + iouc + prior;
  return valid ? c : 1e8f;
}

// ---------- fast path kernel 0: stage score rows in LDS, emit xT columns + valid mask + zero bitmask ----------

__global__ void __launch_bounds__(PDIM) k_prep(
    const float* __restrict__ pred_scores,
    const float* __restrict__ priors,
    const int*   __restrict__ gt_labels,
    const float* __restrict__ gt_bboxes,
    const float* __restrict__ pad_flag,
    unsigned char* __restrict__ valid_mask,
    uint32_t* __restrict__ match_mask,
    float* __restrict__ xT)
{
  int b = blockIdx.y;
  int nbase = blockIdx.x * PDIM;
  int tid = threadIdx.x;
  int rows = N_ - nbase; if (rows > PDIM) rows = PDIM;

  __shared__ float  srow[PDIM * LDS_STRIDE];   // 128 x 81 floats = 41.5 KB
  __shared__ float4 sbox[G_];
  __shared__ float  sflag[G_];
  __shared__ int    slbl[G_];

  for (int g = tid; g < G_; g += PDIM){
    sbox[g]  = ((const float4*)gt_bboxes)[b*G_ + g];
    sflag[g] = pad_flag[b*G_ + g];
    slbl[g]  = gt_labels[b*G_ + g];
  }

  // cooperative coalesced load of `rows` contiguous score rows -> padded LDS
  const float4* src4 = (const float4*)(pred_scores + ((size_t)b*N_ + nbase)*(size_t)NCLS);
  int nf4 = rows * (NCLS/4);
  for (int fi = tid; fi < nf4; fi += PDIM){
    float4 v = src4[fi];
    int row = fi / (NCLS/4);
    int col = (fi - row*(NCLS/4)) * 4;
    float* dst = srow + row*LDS_STRIDE + col;
    dst[0] = v.x; dst[1] = v.y; dst[2] = v.z; dst[3] = v.w;  // scalar writes keep odd stride OK
  }
  __syncthreads();

  int n = nbase + tid;
  if (tid < rows){
    // emit all G columns: LDS read stride-81 (conflict-free), global write coalesced
    const float* myrow = srow + tid*LDS_STRIDE;
    for (int g = 0; g < G_; ++g){
      xT[((size_t)b*G_ + g)*(size_t)N_ + n] = myrow[slbl[g]];
    }
    // valid mask (anchor strictly inside any valid gt)
    float cx = priors[n*4+0], cy = priors[n*4+1];
    bool v = false;
    for (int g = 0; g < G_; ++g){
      float4 gb = sbox[g];
      bool in = (cx - gb.x > 0.0f) & (cy - gb.y > 0.0f) &
                (gb.z - cx > 0.0f) & (gb.w - cy > 0.0f) & (sflag[g] > 0.0f);
      v |= in;
    }
    size_t idx = (size_t)b*N_ + n;
    valid_mask[idx] = v ? 1 : 0;
    ((uint4*)match_mask)[idx] = make_uint4(0u,0u,0u,0u);
  }
}

// ---------- fallback kernel 0 ----------

__global__ void __launch_bounds__(BDIM) k_validmask(
    const float* __restrict__ priors,
    const float* __restrict__ gt_bboxes,
    const float* __restrict__ pad_flag,
    unsigned char* __restrict__ valid_mask,
    uint32_t* __restrict__ match_mask)
{
  int b = blockIdx.y;
  __shared__ float4 sbox[G_];
  __shared__ float  sflag[G_];
  for (int g = threadIdx.x; g < G_; g += BDIM){
    sbox[g]  = ((const float4*)gt_bboxes)[b*G_ + g];
    sflag[g] = pad_flag[b*G_ + g];
  }
  __syncthreads();
  int n = blockIdx.x*BDIM + threadIdx.x;
  if (n >= N_) return;
  float cx = priors[n*4+0], cy = priors[n*4+1];
  bool v = false;
  for (int g = 0; g < G_; ++g){
    float4 gb = sbox[g];
    bool in = (cx - gb.x > 0.0f) & (cy - gb.y > 0.0f) &
              (gb.z - cx > 0.0f) & (gb.w - cy > 0.0f) & (sflag[g] > 0.0f);
    v |= in;
  }
  size_t idx = (size_t)b*N_ + n;
  valid_mask[idx] = v ? 1 : 0;
  ((uint4*)match_mask)[idx] = make_uint4(0u,0u,0u,0u);
}

// ---------- kernel 1: per (b,g) top-13 cost candidates + dyn_k, scatter match bits ----------

template<bool USE_XT>
__global__ void __launch_bounds__(BDIM) k_topk(
    const float* __restrict__ pred_bboxes,
    const float* __restrict__ pred_scores,
    const float* __restrict__ priors,
    const int*   __restrict__ gt_labels,
    const float* __restrict__ gt_bboxes,
    const float* __restrict__ pad_flag,
    const unsigned char* __restrict__ valid_mask,
    uint32_t* __restrict__ match_mask,
    const float* __restrict__ xT)
{
  #pragma clang fp contract(off)
  int g = blockIdx.x, b = blockIdx.y;
  if (pad_flag[b*G_ + g] <= 0.0f) return;   // invalid gt: contributes no matches

  float4 gb = ((const float4*)gt_bboxes)[b*G_ + g];
  float ga  = (gb.z - gb.x) * (gb.w - gb.y);
  float gcx = (gb.x + gb.z) * 0.5f, gcy = (gb.y + gb.w) * 0.5f;
  int   lbl = gt_labels[b*G_ + g];
  int   tid = threadIdx.x;
  const float* xcol = xT + ((size_t)b*G_ + g)*(size_t)N_;

  unsigned long long ck[TOPK_];  // smallest 13 (cost,idx) keys, ascending
  float ti[TOPK_];               // largest 13 ious, descending
  #pragma unroll
  for (int j = 0; j < TOPK_; ++j){ ck[j] = ~0ull; ti[j] = -1.0f; }

  for (int n = tid; n < N_; n += BDIM){
    size_t idx = (size_t)b*N_ + n;
    float4 pb = ((const float4*)pred_bboxes)[idx];
    float pa  = (pb.z - pb.x) * (pb.w - pb.y);
    float iou = iou_pair(pb, pa, gb, ga);

    if (iou > ti[TOPK_-1]){                     // insert into descending list
      float nt[TOPK_];
      #pragma unroll
      for (int j = 0; j < TOPK_; ++j){
        float prev = (j == 0) ? 0.0f : ti[j-1];
        nt[j] = (iou <= ti[j]) ? ti[j] : ((j == 0 || iou <= prev) ? iou : prev);
      }
      #pragma unroll
      for (int j = 0; j < TOPK_; ++j) ti[j] = nt[j];
    }

    float4 pr = ((const float4*)priors)[n];
    bool valid = valid_mask[idx] != 0;
    float dx = pr.x - gcx, dy = pr.y - gcy;
    float dist = sqrtf(dx*dx + dy*dy) / pr.z;
    float x = USE_XT ? xcol[n] : pred_scores[idx*(size_t)NCLS + lbl];
    float c = cost_eval(iou, x, dist, valid);
    unsigned long long key = ((unsigned long long)fkey(c) << 32) | (unsigned int)n;

    if (key < ck[TOPK_-1]){                     // insert into ascending list
      unsigned long long nk[TOPK_];
      #pragma unroll
      for (int j = 0; j < TOPK_; ++j){
        unsigned long long prev = (j == 0) ? 0ull : ck[j-1];
        nk[j] = (key >= ck[j]) ? ck[j] : ((j == 0 || key >= prev) ? key : prev);
      }
      #pragma unroll
      for (int j = 0; j < TOPK_; ++j) ck[j] = nk[j];
    }
  }

  // block tree-merge: cost keys
  __shared__ unsigned long long sk[BDIM][TOPK_];
  #pragma unroll
  for (int j = 0; j < TOPK_; ++j) sk[tid][j] = ck[j];
  for (int off = BDIM/2; off > 0; off >>= 1){
    __syncthreads();
    if (tid < off){
      unsigned long long m[TOPK_];
      int i1 = 0, i2 = 0;
      #pragma unroll
      for (int j = 0; j < TOPK_; ++j){
        unsigned long long a = sk[tid][i1], c2 = sk[tid+off][i2];
        if (a <= c2){ m[j] = a; ++i1; } else { m[j] = c2; ++i2; }
      }
      #pragma unroll
      for (int j = 0; j < TOPK_; ++j) sk[tid][j] = m[j];
    }
  }

  // block tree-merge: iou top-13 (descending)
  __shared__ float si[BDIM][TOPK_];
  #pragma unroll
  for (int j = 0; j < TOPK_; ++j) si[tid][j] = ti[j];
  for (int off = BDIM/2; off > 0; off >>= 1){
    __syncthreads();
    if (tid < off){
      float m[TOPK_];
      int i1 = 0, i2 = 0;
      #pragma unroll
      for (int j = 0; j < TOPK_; ++j){
        float a = si[tid][i1], c2 = si[tid+off][i2];
        if (a >= c2){ m[j] = a; ++i1; } else { m[j] = c2; ++i2; }
      }
      #pragma unroll
      for (int j = 0; j < TOPK_; ++j) si[tid][j] = m[j];
    }
  }
  __syncthreads();

  if (tid == 0){
    float s = 0.0f;
    #pragma unroll
    for (int j = 0; j < TOPK_; ++j) s += si[0][j];   // descending order sum (matches top_k output order)
    int dynk = (int)s;                                // trunc toward zero
    if (dynk < 1) dynk = 1;
    if (dynk > TOPK_) dynk = TOPK_;
    for (int j = 0; j < dynk; ++j){
      int n = (int)(sk[0][j] & 0xffffffffu);
      atomicOr(&match_mask[((size_t)b*N_ + n)*4 + (g >> 5)], 1u << (g & 31));
    }
  }
}

// ---------- kernel 2: per (b,n) final assignment ----------

template<bool USE_XT>
__global__ void __launch_bounds__(BDIM) k_assign(
    const float* __restrict__ pred_bboxes,
    const float* __restrict__ pred_scores,
    const float* __restrict__ priors,
    const int*   __restrict__ gt_labels,
    const float* __restrict__ gt_bboxes,
    const unsigned char* __restrict__ valid_mask,
    const uint32_t* __restrict__ match_mask,
    const float* __restrict__ xT,
    float* __restrict__ out)
{
  #pragma clang fp contract(off)
  int b = blockIdx.y;
  __shared__ float4 sbox[G_];
  __shared__ int    slbl[G_];
  __shared__ float  sga[G_], sgcx[G_], sgcy[G_];
  for (int g = threadIdx.x; g < G_; g += BDIM){
    float4 gb = ((const float4*)gt_bboxes)[b*G_ + g];
    sbox[g] = gb;
    slbl[g] = gt_labels[b*G_ + g];
    sga[g]  = (gb.z - gb.x) * (gb.w - gb.y);
    sgcx[g] = (gb.x + gb.z) * 0.5f;
    sgcy[g] = (gb.y + gb.w) * 0.5f;
  }
  __syncthreads();
  int n = blockIdx.x*BDIM + threadIdx.x;
  if (n >= N_) return;

  size_t idx = (size_t)b*N_ + n;
  uint4 mm = ((const uint4*)match_mask)[idx];
  int count = __popc(mm.x) + __popc(mm.y) + __popc(mm.z) + __popc(mm.w);
  float4 pb = ((const float4*)pred_bboxes)[idx];
  float pa  = (pb.z - pb.x) * (pb.w - pb.y);
  float4 pr = ((const float4*)priors)[n];
  bool valid = valid_mask[idx] != 0;
  const float* srow = pred_scores + idx*(size_t)NCLS;
  const float* xcolb = xT + (size_t)b*G_*(size_t)N_ + n;

  float minc = 0.0f; int amin = 0; float iou_amin = 0.0f; float iou_sum = 0.0f;
  bool first = true;
  #pragma unroll
  for (int w = 0; w < 4; ++w){
    uint32_t word = (w == 0) ? mm.x : (w == 1) ? mm.y : (w == 2) ? mm.z : mm.w;
    const int glim = (w < 3) ? 32 : (G_ - 96);
    for (int g2 = 0; g2 < glim; ++g2){
      int g = w*32 + g2;
      float4 gb = sbox[g];
      float iou = iou_pair(pb, pa, gb, sga[g]);
      float dx = pr.x - sgcx[g], dy = pr.y - sgcy[g];
      float dist = sqrtf(dx*dx + dy*dy) / pr.z;
      float x = USE_XT ? xcolb[(size_t)g*N_] : srow[slbl[g]];
      float c = cost_eval(iou, x, dist, valid);
      if (first || c < minc){ minc = c; amin = g; iou_amin = iou; first = false; }
      if ((word >> g2) & 1u) iou_sum += iou;
    }
  }

  bool multi = count > 1;
  int mg; float mi; bool fg;
  if (multi){ mg = amin; mi = iou_amin; fg = true; }       // onehot at argmin
  else {
    fg = count > 0;
    mg = mm.x ? (__ffs(mm.x) - 1) :
         mm.y ? (31 + __ffs(mm.y)) :
         mm.z ? (63 + __ffs(mm.z)) :
         mm.w ? (95 + __ffs(mm.w)) : 0;
    mi = iou_sum;                                           // <=1 term, exact
  }

  out[idx] = fg ? (float)slbl[mg] : (float)NCLS;           // assigned_labels
  out[(size_t)B_*N_ + idx] = 1.0f;                          // weights
  float4 ob = fg ? sbox[mg] : make_float4(0.f,0.f,0.f,0.f);
  ((float4*)(out + (size_t)2*B_*N_))[idx] = ob;             // assigned_bboxes
  out[(size_t)6*B_*N_ + idx] = fg ? mi : 0.0f;              // assign_metrics
}

// ---------- launch ----------

extern "C" void kernel_launch(void* const* d_in, const int* in_sizes, int n_in,
                              void* d_out, int out_size, void* d_ws, size_t ws_size,
                              hipStream_t stream) {
  const float* pred_bboxes = (const float*)d_in[0];
  const float* pred_scores = (const float*)d_in[1];
  const float* priors      = (const float*)d_in[2];
  const int*   gt_labels   = (const int*)  d_in[3];
  const float* gt_bboxes   = (const float*)d_in[4];
  const float* pad_flag    = (const float*)d_in[5];
  float* out = (float*)d_out;

  // ws layout: match bitmask (B*N*4 u32) | valid mask (B*N bytes) | xT (B*G*N floats)
  const size_t MASK_B  = (size_t)B_*N_*4*sizeof(uint32_t);      // 4,300,800
  const size_t VALID_B = (size_t)B_*N_;                          //   268,800
  const size_t XT_B    = (size_t)B_*G_*N_*sizeof(float);         // 107,520,000
  uint32_t* match_mask = (uint32_t*)d_ws;
  unsigned char* valid_mask = (unsigned char*)d_ws + MASK_B;
  float* xT = (float*)((char*)d_ws + MASK_B + VALID_B);
  bool use_xt = ws_size >= MASK_B + VALID_B + XT_B;

  dim3 gridN((N_ + BDIM - 1)/BDIM, B_);
  dim3 gridG(G_, B_);

  if (use_xt){
    dim3 gridP((N_ + PDIM - 1)/PDIM, B_);
    k_prep<<<gridP, PDIM, 0, stream>>>(pred_scores, priors, gt_labels, gt_bboxes,
                                       pad_flag, valid_mask, match_mask, xT);
    k_topk<true><<<gridG, BDIM, 0, stream>>>(pred_bboxes, pred_scores, priors, gt_labels,
                                             gt_bboxes, pad_flag, valid_mask, match_mask, xT);
    k_assign<true><<<gridN, BDIM, 0, stream>>>(pred_bboxes, pred_scores, priors, gt_labels,
                                               gt_bboxes, valid_mask, match_mask, xT, out);
  } else {
    k_validmask<<<gridN, BDIM, 0, stream>>>(priors, gt_bboxes, pad_flag, valid_mask, match_mask);
    k_topk<false><<<gridG, BDIM, 0, stream>>>(pred_bboxes, pred_scores, priors, gt_labels,
                                              gt_bboxes, pad_flag, valid_mask, match_mask, xT);
    k_assign<false><<<gridN, BDIM, 0, stream>>>(pred_bboxes, pred_scores, priors, gt_labels,
                                                gt_bboxes, valid_mask, match_mask, xT, out);
  }
}

// Round 3
// 304.859 us; speedup vs baseline: 2.1889x; 1.6246x over previous
//
#include <hip/hip_runtime.h>
#include <stdint.h>

#define BDIM 256
#define B_   8
#define NCLS 80
#define G_   100
#define N_   33600
#define TOPK_ 13
#define CAPC 160     // per-wave cost candidate buffer (u64 keys)
#define CAPI 160     // per-wave iou candidate buffer (f32)
#define INFC 1e8f

// ---------- helpers ----------

__device__ __forceinline__ unsigned int fkey(float f){
  unsigned int u = __float_as_uint(f);
  return (u & 0x80000000u) ? ~u : (u | 0x80000000u);  // monotonic float->uint
}
__device__ __forceinline__ float unfkey(unsigned int k){
  unsigned int u = (k & 0x80000000u) ? (k & 0x7fffffffu) : ~k;
  return __uint_as_float(u);
}

// cost = bce*(scale^2) + (-log(iou+eps)*3) + 10^(dist-3); INF-masked by valid
__device__ __forceinline__ float cost_eval(float iou, float x, float dist, bool valid){
  #pragma clang fp contract(off)
  float prior = exp2f((dist - 3.0f) * 3.321928094887362f);   // 10^(dist-3)
  float iouc  = -logf(iou + 1e-7f) * 3.0f;
  float sig   = 1.0f / (1.0f + expf(-x));
  float sc    = iou - sig;
  float bce   = fmaxf(x, 0.0f) + log1pf(expf(-fabsf(x))) - x * iou;
  float c     = bce * (sc * sc) + iouc + prior;
  return valid ? c : INFC;
}

// exact selection of 13 smallest u64 keys from buf[0..cnt) (cnt<=CAPC<=192).
// Slots held in registers; extraction via wave shuffle min-reduce. Writes the
// 13 ascending to buf[0..13). Returns the 13th smallest (new threshold).
__device__ unsigned long long compact_cost(unsigned long long* buf, int cnt){
  const int lane = threadIdx.x & 63;
  unsigned long long a0 = (lane       < cnt) ? buf[lane]       : ~0ull;
  unsigned long long a1 = (lane + 64  < cnt) ? buf[lane + 64]  : ~0ull;
  unsigned long long a2 = (lane + 128 < cnt) ? buf[lane + 128] : ~0ull;
  unsigned long long mykeep = ~0ull, t13 = ~0ull;
  #pragma unroll
  for (int r = 0; r < TOPK_; ++r){
    unsigned long long v = a0 < a1 ? a0 : a1; v = v < a2 ? v : a2;
    unsigned long long mn = v;
    #pragma unroll
    for (int m = 1; m < 64; m <<= 1){
      unsigned int lo = (unsigned int)__shfl_xor((int)(unsigned int)mn, m, 64);
      unsigned int hi = (unsigned int)__shfl_xor((int)(unsigned int)(mn >> 32), m, 64);
      unsigned long long o = ((unsigned long long)hi << 32) | lo;
      mn = o < mn ? o : mn;
    }
    if      (a0 == mn) a0 = ~0ull;   // keys unique: exactly one real slot matches
    else if (a1 == mn) a1 = ~0ull;
    else if (a2 == mn) a2 = ~0ull;
    if (lane == r) mykeep = mn;
    t13 = mn;
  }
  if (lane < TOPK_) buf[lane] = mykeep;
  return t13;
}

// exact selection of 13 largest floats (dups allowed) from buf[0..cnt).
// Writes 13 descending to buf[0..13). Returns 13th largest.
__device__ float compact_iou(float* buf, int cnt){
  const int lane = threadIdx.x & 63;
  float a0 = (lane       < cnt) ? buf[lane]       : -1.0f;
  float a1 = (lane + 64  < cnt) ? buf[lane + 64]  : -1.0f;
  float a2 = (lane + 128 < cnt) ? buf[lane + 128] : -1.0f;
  float mykeep = -1.0f, t13 = -1.0f;
  #pragma unroll
  for (int r = 0; r < TOPK_; ++r){
    float mx = fmaxf(fmaxf(a0, a1), a2);
    #pragma unroll
    for (int m = 1; m < 64; m <<= 1) mx = fmaxf(mx, __shfl_xor(mx, m, 64));
    bool h0 = (a0 == mx), h1 = (a1 == mx), h2 = (a2 == mx);
    unsigned long long ball = __ballot(h0 | h1 | h2);
    int src = (int)(__ffsll(ball) - 1);
    if (lane == src){                      // clear exactly one instance
      if (h0) a0 = -1.0f; else if (h1) a1 = -1.0f; else a2 = -1.0f;
    }
    if (lane == r) mykeep = mx;
    t13 = mx;
  }
  if (lane < TOPK_) buf[lane] = mykeep;
  return t13;
}

// ---------- kernel 0: valid mask + zero bitmask ----------

__global__ void __launch_bounds__(BDIM) k_validmask(
    const float* __restrict__ priors,
    const float* __restrict__ gt_bboxes,
    const float* __restrict__ pad_flag,
    unsigned char* __restrict__ valid_mask,
    uint32_t* __restrict__ match_mask)
{
  int b = blockIdx.y;
  __shared__ float4 sbox[G_];
  __shared__ float  sflag[G_];
  for (int g = threadIdx.x; g < G_; g += BDIM){
    sbox[g]  = ((const float4*)gt_bboxes)[b*G_ + g];
    sflag[g] = pad_flag[b*G_ + g];
  }
  __syncthreads();
  int n = blockIdx.x*BDIM + threadIdx.x;
  if (n >= N_) return;
  float cx = priors[n*4+0], cy = priors[n*4+1];
  bool v = false;
  for (int g = 0; g < G_; ++g){
    float4 gb = sbox[g];
    bool in = (cx - gb.x > 0.0f) & (cy - gb.y > 0.0f) &
              (gb.z - cx > 0.0f) & (gb.w - cy > 0.0f) & (sflag[g] > 0.0f);
    v |= in;
  }
  size_t idx = (size_t)b*N_ + n;
  valid_mask[idx] = v ? 1 : 0;
  ((uint4*)match_mask)[idx] = make_uint4(0u,0u,0u,0u);
}

// ---------- kernel 1: per (b,g) wave-cooperative streaming top-13 ----------

__global__ void __launch_bounds__(BDIM) k_topk(
    const float* __restrict__ pred_bboxes,
    const float* __restrict__ pred_scores,
    const float* __restrict__ priors,
    const int*   __restrict__ gt_labels,
    const float* __restrict__ gt_bboxes,
    const float* __restrict__ pad_flag,
    const unsigned char* __restrict__ valid_mask,
    uint32_t* __restrict__ match_mask)
{
  #pragma clang fp contract(off)
  const int g = blockIdx.x, b = blockIdx.y;
  if (pad_flag[b*G_ + g] <= 0.0f) return;   // invalid gt: no matches

  __shared__ unsigned long long s_cbuf[4][CAPC];
  __shared__ float s_ibuf[4][CAPI];
  __shared__ unsigned long long s_fk[4][TOPK_ + 1];
  __shared__ float s_fi[4][TOPK_ + 1];

  const int tid = threadIdx.x, lane = tid & 63, wid = tid >> 6;
  unsigned long long* cbuf = s_cbuf[wid];
  float* ibuf = s_ibuf[wid];

  const float4 gb = ((const float4*)gt_bboxes)[b*G_ + g];
  const float ga  = (gb.z - gb.x) * (gb.w - gb.y);
  const float gcx = (gb.x + gb.z) * 0.5f, gcy = (gb.y + gb.w) * 0.5f;
  const int lbl = gt_labels[b*G_ + g];
  const unsigned int KEYINF = fkey(INFC);

  // running thresholds (wave-uniform registers)
  unsigned long long Tkey = ~0ull;   // exact 13th-smallest (cost,idx) key so far
  bool  tc48  = false;               // Tc < 48 => iou==0 anchors provably out
  float gthr2 = 1e30f;               // (3+log10(Tc)+0.02)^2 dist-gate (strides^2)
  float Tiou_m = 0.0f;               // conservative iou gate threshold
  int ccnt = 0, icnt = 0;

  const float4* pb4 = (const float4*)pred_bboxes + (size_t)b*N_;
  const float4* pr4 = (const float4*)priors;
  const unsigned char* vm = valid_mask + (size_t)b*N_;
  const float* sc_b = pred_scores + (size_t)b*N_*NCLS;

  for (int n = tid; n < N_; n += BDIM){
    float4 pb = pb4[n];
    float4 pr = pr4[n];
    float pa = (pb.z - pb.x) * (pb.w - pb.y);
    float lx = fmaxf(pb.x, gb.x), ly = fmaxf(pb.y, gb.y);
    float rx = fminf(pb.z, gb.z), ry = fminf(pb.w, gb.w);
    float ov = fmaxf(rx - lx, 0.0f) * fmaxf(ry - ly, 0.0f);
    float un = pa + ga - ov;                      // un >= max(pa,ga) > 0
    bool ipass = ov > Tiou_m * un;                // superset of {iou > Tiou}

    float invs = __uint_as_float(0x7F000000u - __float_as_uint(pr.z)); // exact 1/2^k
    float dx = pr.x - gcx, dy = pr.y - gcy;
    float dist2 = dx*dx + dy*dy;
    float d2s = dist2 * (invs * invs);
    bool valid = vm[n] != 0;
    // conservative: skip iff provably cost > Tc
    bool needcost = valid && (d2s <= gthr2) && !((ov <= 0.0f) && tc48);

    float iou = 0.0f;
    if (__any(ipass || needcost)){
      if (ipass || needcost) iou = ov / fmaxf(un, 1e-6f);
    }

    // ---- iou top-13 stream (values only; sum feeds dyn_k) ----
    {
      unsigned long long m = __ballot(ipass);
      if (m){
        int pc = __popcll(m);
        if (icnt + pc > CAPI){
          float t = compact_iou(ibuf, icnt); icnt = TOPK_;
          Tiou_m = t * 0.999f;                     // conservative down
        }
        int pos = icnt + (int)__popcll(m & ((1ull << lane) - 1ull));
        if (ipass) ibuf[pos] = iou;
        icnt += pc;
      }
    }

    // ---- cost top-13 stream ----
    unsigned long long key = ((unsigned long long)KEYINF << 32) | (unsigned)n;
    bool cpass = (!valid) && (key < Tkey);         // invalid: cost == 1e8 exactly
    if (__any(needcost)){
      if (needcost){
        float x = sc_b[(size_t)n*NCLS + lbl];
        float dist = sqrtf(dist2) * invs;          // == sqrt(d2)/stride exactly
        float c = cost_eval(iou, x, dist, true);
        key = ((unsigned long long)fkey(c) << 32) | (unsigned)n;
        cpass = key < Tkey;
      }
    }
    {
      unsigned long long m = __ballot(cpass);
      if (m){
        int pc = __popcll(m);
        if (ccnt + pc > CAPC){
          Tkey = compact_cost(cbuf, ccnt); ccnt = TOPK_;
          float Tc = unfkey((unsigned int)(Tkey >> 32));
          tc48 = Tc < 48.0f;                        // iou=0 => cost > 48.35
          float gt_ = 3.02f + log10f(Tc);           // +0.02 conservative margin
          gthr2 = (gt_ > 0.0f) ? gt_*gt_ : 1e30f;
        }
        int pos = ccnt + (int)__popcll(m & ((1ull << lane) - 1ull));
        if (cpass) cbuf[pos] = key;
        ccnt += pc;
      }
    }
  }

  // final per-wave exact selection, then cross-wave merge
  compact_cost(cbuf, ccnt);
  compact_iou(ibuf, icnt);
  if (lane < TOPK_){ s_fk[wid][lane] = cbuf[lane]; s_fi[wid][lane] = ibuf[lane]; }
  if (lane == TOPK_){ s_fk[wid][TOPK_] = ~0ull; s_fi[wid][TOPK_] = -1e30f; }
  __syncthreads();

  if (tid == 0){
    // merge 4 descending iou lists; sum top-13 in descending order
    int p0 = 0, p1 = 0, p2 = 0, p3 = 0; float s = 0.0f;
    for (int r = 0; r < TOPK_; ++r){
      float v0 = s_fi[0][p0], v1 = s_fi[1][p1], v2 = s_fi[2][p2], v3 = s_fi[3][p3];
      float mx = fmaxf(fmaxf(v0, v1), fmaxf(v2, v3));
      if      (v0 == mx) p0++;
      else if (v1 == mx) p1++;
      else if (v2 == mx) p2++;
      else               p3++;
      s += fmaxf(mx, 0.0f);                        // sentinels add 0
    }
    int dynk = (int)s;                             // trunc toward zero
    if (dynk < 1) dynk = 1;
    if (dynk > TOPK_) dynk = TOPK_;
    // merge 4 ascending key lists; scatter first dynk
    int q0 = 0, q1 = 0, q2 = 0, q3 = 0;
    for (int r = 0; r < dynk; ++r){
      unsigned long long k0 = s_fk[0][q0], k1 = s_fk[1][q1];
      unsigned long long k2 = s_fk[2][q2], k3 = s_fk[3][q3];
      unsigned long long mn = k0 < k1 ? k0 : k1;
      unsigned long long mn2 = k2 < k3 ? k2 : k3;
      mn = mn < mn2 ? mn : mn2;
      if      (k0 == mn) q0++;
      else if (k1 == mn) q1++;
      else if (k2 == mn) q2++;
      else               q3++;
      int n = (int)(mn & 0xffffffffu);
      atomicOr(&match_mask[((size_t)b*N_ + n)*4 + (g >> 5)], 1u << (g & 31));
    }
  }
}

// ---------- kernel 2: per (b,n) final assignment (count==0 fast path) ----------

__global__ void __launch_bounds__(BDIM) k_assign(
    const float* __restrict__ pred_bboxes,
    const float* __restrict__ pred_scores,
    const float* __restrict__ priors,
    const int*   __restrict__ gt_labels,
    const float* __restrict__ gt_bboxes,
    const unsigned char* __restrict__ valid_mask,
    const uint32_t* __restrict__ match_mask,
    float* __restrict__ out)
{
  #pragma clang fp contract(off)
  const int b = blockIdx.y;
  __shared__ float4 sbox[G_];
  __shared__ int    slbl[G_];
  __shared__ float  sga[G_], sgcx[G_], sgcy[G_];
  for (int g = threadIdx.x; g < G_; g += BDIM){
    float4 q = ((const float4*)gt_bboxes)[b*G_ + g];
    sbox[g] = q; slbl[g] = gt_labels[b*G_ + g];
    sga[g]  = (q.z - q.x) * (q.w - q.y);
    sgcx[g] = (q.x + q.z) * 0.5f;
    sgcy[g] = (q.y + q.w) * 0.5f;
  }
  __syncthreads();
  int n = blockIdx.x*BDIM + threadIdx.x;
  if (n >= N_) return;
  size_t idx = (size_t)b*N_ + n;
  uint4 mm = ((const uint4*)match_mask)[idx];
  int count = __popc(mm.x) + __popc(mm.y) + __popc(mm.z) + __popc(mm.w);

  float lblv = (float)NCLS;
  float4 ob = make_float4(0.f, 0.f, 0.f, 0.f);
  float met = 0.0f;

  if (__any(count > 0)){
    float4 pb = make_float4(0.f,0.f,0.f,0.f); float pa = 0.0f;
    if (count > 0){
      pb = ((const float4*)pred_bboxes)[idx];
      pa = (pb.z - pb.x) * (pb.w - pb.y);
    }
    if (count == 1){
      int mg = mm.x ? (__ffs(mm.x) - 1) :
               mm.y ? (31 + __ffs(mm.y)) :
               mm.z ? (63 + __ffs(mm.z)) : (95 + __ffs(mm.w));
      float4 q = sbox[mg];
      float lx = fmaxf(pb.x, q.x), ly = fmaxf(pb.y, q.y);
      float rx = fminf(pb.z, q.z), ry = fminf(pb.w, q.w);
      float ov = fmaxf(rx - lx, 0.0f) * fmaxf(ry - ly, 0.0f);
      float iou = ov / fmaxf(pa + sga[mg] - ov, 1e-6f);
      lblv = (float)slbl[mg]; ob = q; met = iou;
    }
    if (__any(count > 1)){
      if (count > 1){
        float4 pr = ((const float4*)priors)[n];
        float invs = __uint_as_float(0x7F000000u - __float_as_uint(pr.z));
        bool valid = valid_mask[idx] != 0;
        const float* srow = pred_scores + idx*(size_t)NCLS;
        float minc = 0.0f; int amin = 0; float iamin = 0.0f;
        for (int g = 0; g < G_; ++g){
          float4 q = sbox[g];
          float lx = fmaxf(pb.x, q.x), ly = fmaxf(pb.y, q.y);
          float rx = fminf(pb.z, q.z), ry = fminf(pb.w, q.w);
          float ov = fmaxf(rx - lx, 0.0f) * fmaxf(ry - ly, 0.0f);
          float un = pa + sga[g] - ov;
          float iou = ov / fmaxf(un, 1e-6f);
          float dx = pr.x - sgcx[g], dy = pr.y - sgcy[g];
          float dist = sqrtf(dx*dx + dy*dy) * invs;
          float c = cost_eval(iou, srow[slbl[g]], dist, valid);
          bool better = (g == 0) || (c < minc);
          if (better){ minc = c; amin = g; iamin = iou; }
        }
        lblv = (float)slbl[amin]; ob = sbox[amin]; met = iamin;
      }
    }
  }

  out[idx] = lblv;                                   // assigned_labels
  out[(size_t)B_*N_ + idx] = 1.0f;                   // weights
  ((float4*)(out + (size_t)2*B_*N_))[idx] = ob;      // assigned_bboxes
  out[(size_t)6*B_*N_ + idx] = met;                  // assign_metrics
}

// ---------- launch ----------

extern "C" void kernel_launch(void* const* d_in, const int* in_sizes, int n_in,
                              void* d_out, int out_size, void* d_ws, size_t ws_size,
                              hipStream_t stream) {
  const float* pred_bboxes = (const float*)d_in[0];
  const float* pred_scores = (const float*)d_in[1];
  const float* priors      = (const float*)d_in[2];
  const int*   gt_labels   = (const int*)  d_in[3];
  const float* gt_bboxes   = (const float*)d_in[4];
  const float* pad_flag    = (const float*)d_in[5];
  float* out = (float*)d_out;

  // ws layout: match bitmask (B*N*4 u32 = 4,300,800 B) | valid mask (B*N bytes)
  const size_t MASK_B = (size_t)B_*N_*4*sizeof(uint32_t);
  uint32_t* match_mask = (uint32_t*)d_ws;
  unsigned char* valid_mask = (unsigned char*)d_ws + MASK_B;

  dim3 gridN((N_ + BDIM - 1)/BDIM, B_);
  dim3 gridG(G_, B_);

  k_validmask<<<gridN, BDIM, 0, stream>>>(priors, gt_bboxes, pad_flag,
                                          valid_mask, match_mask);
  k_topk<<<gridG, BDIM, 0, stream>>>(pred_bboxes, pred_scores, priors, gt_labels,
                                     gt_bboxes, pad_flag, valid_mask, match_mask);
  k_assign<<<gridN, BDIM, 0, stream>>>(pred_bboxes, pred_scores, priors, gt_labels,
                                       gt_bboxes, valid_mask, match_mask, out);
}

// Round 4
// 140.975 us; speedup vs baseline: 4.7336x; 2.1625x over previous
//
#include <hip/hip_runtime.h>
#include <stdint.h>

#define BDIM 256
#define B_   8
#define NCLS 80
#define G_   100
#define N_   33600
#define TOPK_ 13
#define CAPC 160     // per-wave cost candidate buffer (u64 keys)
#define CAPI 160     // per-wave iou candidate buffer (f32)
#define INFC 1e8f

// ---------- helpers ----------

__device__ __forceinline__ unsigned int fkey(float f){
  unsigned int u = __float_as_uint(f);
  return (u & 0x80000000u) ? ~u : (u | 0x80000000u);  // monotonic float->uint
}
__device__ __forceinline__ float unfkey(unsigned int k){
  unsigned int u = (k & 0x80000000u) ? (k & 0x7fffffffu) : ~k;
  return __uint_as_float(u);
}

// cost = bce*(scale^2) + (-log(iou+eps)*3) + 10^(dist-3); INF-masked by valid
__device__ __forceinline__ float cost_eval(float iou, float x, float dist, bool valid){
  #pragma clang fp contract(off)
  float prior = exp2f((dist - 3.0f) * 3.321928094887362f);   // 10^(dist-3)
  float iouc  = -logf(iou + 1e-7f) * 3.0f;
  float sig   = 1.0f / (1.0f + expf(-x));
  float sc    = iou - sig;
  float bce   = fmaxf(x, 0.0f) + log1pf(expf(-fabsf(x))) - x * iou;
  float c     = bce * (sc * sc) + iouc + prior;
  return valid ? c : INFC;
}

// exact selection of 13 smallest u64 keys from buf[0..cnt) (cnt<=CAPC<=192).
__device__ unsigned long long compact_cost(unsigned long long* buf, int cnt){
  const int lane = threadIdx.x & 63;
  unsigned long long a0 = (lane       < cnt) ? buf[lane]       : ~0ull;
  unsigned long long a1 = (lane + 64  < cnt) ? buf[lane + 64]  : ~0ull;
  unsigned long long a2 = (lane + 128 < cnt) ? buf[lane + 128] : ~0ull;
  unsigned long long mykeep = ~0ull, t13 = ~0ull;
  #pragma unroll
  for (int r = 0; r < TOPK_; ++r){
    unsigned long long v = a0 < a1 ? a0 : a1; v = v < a2 ? v : a2;
    unsigned long long mn = v;
    #pragma unroll
    for (int m = 1; m < 64; m <<= 1){
      unsigned int lo = (unsigned int)__shfl_xor((int)(unsigned int)mn, m, 64);
      unsigned int hi = (unsigned int)__shfl_xor((int)(unsigned int)(mn >> 32), m, 64);
      unsigned long long o = ((unsigned long long)hi << 32) | lo;
      mn = o < mn ? o : mn;
    }
    if      (a0 == mn) a0 = ~0ull;   // keys unique: exactly one real slot matches
    else if (a1 == mn) a1 = ~0ull;
    else if (a2 == mn) a2 = ~0ull;
    if (lane == r) mykeep = mn;
    t13 = mn;
  }
  if (lane < TOPK_) buf[lane] = mykeep;
  return t13;
}

// exact selection of 13 largest floats (dups allowed) from buf[0..cnt).
__device__ float compact_iou(float* buf, int cnt){
  const int lane = threadIdx.x & 63;
  float a0 = (lane       < cnt) ? buf[lane]       : -1.0f;
  float a1 = (lane + 64  < cnt) ? buf[lane + 64]  : -1.0f;
  float a2 = (lane + 128 < cnt) ? buf[lane + 128] : -1.0f;
  float mykeep = -1.0f, t13 = -1.0f;
  #pragma unroll
  for (int r = 0; r < TOPK_; ++r){
    float mx = fmaxf(fmaxf(a0, a1), a2);
    #pragma unroll
    for (int m = 1; m < 64; m <<= 1) mx = fmaxf(mx, __shfl_xor(mx, m, 64));
    bool h0 = (a0 == mx), h1 = (a1 == mx), h2 = (a2 == mx);
    unsigned long long ball = __ballot(h0 | h1 | h2);
    int src = (int)(__ffsll(ball) - 1);
    if (lane == src){                      // clear exactly one instance
      if (h0) a0 = -1.0f; else if (h1) a1 = -1.0f; else a2 = -1.0f;
    }
    if (lane == r) mykeep = mx;
    t13 = mx;
  }
  if (lane < TOPK_) buf[lane] = mykeep;
  return t13;
}

// ---------- kernel 0: valid mask + zero bitmask ----------

__global__ void __launch_bounds__(BDIM) k_validmask(
    const float* __restrict__ priors,
    const float* __restrict__ gt_bboxes,
    const float* __restrict__ pad_flag,
    unsigned char* __restrict__ valid_mask,
    uint32_t* __restrict__ match_mask)
{
  int b = blockIdx.y;
  __shared__ float4 sbox[G_];
  __shared__ float  sflag[G_];
  for (int g = threadIdx.x; g < G_; g += BDIM){
    sbox[g]  = ((const float4*)gt_bboxes)[b*G_ + g];
    sflag[g] = pad_flag[b*G_ + g];
  }
  __syncthreads();
  int n = blockIdx.x*BDIM + threadIdx.x;
  if (n >= N_) return;
  float cx = priors[n*4+0], cy = priors[n*4+1];
  bool v = false;
  for (int g = 0; g < G_; ++g){
    float4 gb = sbox[g];
    bool in = (cx - gb.x > 0.0f) & (cy - gb.y > 0.0f) &
              (gb.z - cx > 0.0f) & (gb.w - cy > 0.0f) & (sflag[g] > 0.0f);
    v |= in;
  }
  size_t idx = (size_t)b*N_ + n;
  valid_mask[idx] = v ? 1 : 0;
  ((uint4*)match_mask)[idx] = make_uint4(0u,0u,0u,0u);
}

// ---------- kernel 1: per (b,g) wave-cooperative streaming top-13 ----------

__global__ void __launch_bounds__(BDIM) k_topk(
    const float* __restrict__ pred_bboxes,
    const float* __restrict__ pred_scores,
    const float* __restrict__ priors,
    const int*   __restrict__ gt_labels,
    const float* __restrict__ gt_bboxes,
    const float* __restrict__ pad_flag,
    const unsigned char* __restrict__ valid_mask,
    uint32_t* __restrict__ match_mask)
{
  #pragma clang fp contract(off)
  const int g = blockIdx.x, b = blockIdx.y;
  if (pad_flag[b*G_ + g] <= 0.0f) return;   // invalid gt: no matches

  __shared__ unsigned long long s_cbuf[4][CAPC];
  __shared__ float s_ibuf[4][CAPI];
  __shared__ unsigned long long s_fk[4][TOPK_ + 1];
  __shared__ float s_fi[4][TOPK_ + 1];

  const int tid = threadIdx.x, lane = tid & 63, wid = tid >> 6;
  unsigned long long* cbuf = s_cbuf[wid];
  float* ibuf = s_ibuf[wid];

  const float4 gb = ((const float4*)gt_bboxes)[b*G_ + g];
  const float ga  = (gb.z - gb.x) * (gb.w - gb.y);
  const float gcx = (gb.x + gb.z) * 0.5f, gcy = (gb.y + gb.w) * 0.5f;
  const int lbl = gt_labels[b*G_ + g];
  const unsigned int KEYINF = fkey(INFC);

  // running thresholds (wave-uniform registers)
  unsigned long long Tkey = ~0ull;   // exact 13th-smallest (cost,idx) key so far
  bool  tc48  = false;               // Tc < 48 => iou==0 anchors provably out
  float gthr2 = 1e30f;               // (3+log10(Tc)+0.02)^2 dist-gate (strides^2)
  float Tiou_m = 0.0f;               // conservative iou gate threshold
  int ccnt = 0, icnt = 0;

  const float4* pb4 = (const float4*)pred_bboxes + (size_t)b*N_;
  const float4* pr4 = (const float4*)priors;
  const unsigned char* vm = valid_mask + (size_t)b*N_;
  const float* sc_b = pred_scores + (size_t)b*N_*NCLS;

  for (int n = tid; n < N_; n += BDIM){
    float4 pb = pb4[n];
    float4 pr = pr4[n];
    float pa = (pb.z - pb.x) * (pb.w - pb.y);
    float lx = fmaxf(pb.x, gb.x), ly = fmaxf(pb.y, gb.y);
    float rx = fminf(pb.z, gb.z), ry = fminf(pb.w, gb.w);
    float ov = fmaxf(rx - lx, 0.0f) * fmaxf(ry - ly, 0.0f);
    float un = pa + ga - ov;                      // un >= max(pa,ga) > 0
    bool ipass = ov > Tiou_m * un;                // superset of {iou > Tiou}

    float invs = __uint_as_float(0x7F000000u - __float_as_uint(pr.z)); // exact 1/2^k
    float dx = pr.x - gcx, dy = pr.y - gcy;
    float dist2 = dx*dx + dy*dy;
    float d2s = dist2 * (invs * invs);
    bool valid = vm[n] != 0;
    // conservative: skip iff provably cost > Tc
    bool needcost = valid && (d2s <= gthr2) && !((ov <= 0.0f) && tc48);

    float iou = 0.0f;
    if (__any(ipass || needcost)){
      if (ipass || needcost) iou = ov / fmaxf(un, 1e-6f);
    }

    // ---- iou top-13 stream (values only; sum feeds dyn_k) ----
    {
      unsigned long long m = __ballot(ipass);
      if (m){
        int pc = __popcll(m);
        if (icnt + pc > CAPI){
          float t = compact_iou(ibuf, icnt); icnt = TOPK_;
          Tiou_m = t * 0.999f;                     // conservative down
        }
        int pos = icnt + (int)__popcll(m & ((1ull << lane) - 1ull));
        if (ipass) ibuf[pos] = iou;
        icnt += pc;
      }
    }

    // ---- cost top-13 stream ----
    unsigned long long key = ((unsigned long long)KEYINF << 32) | (unsigned)n;
    bool cpass = (!valid) && (key < Tkey);         // invalid: cost == 1e8 exactly
    if (__any(needcost)){
      if (needcost){
        float x = sc_b[(size_t)n*NCLS + lbl];
        float dist = sqrtf(dist2) * invs;          // == sqrt(d2)/stride exactly
        float c = cost_eval(iou, x, dist, true);
        key = ((unsigned long long)fkey(c) << 32) | (unsigned)n;
        cpass = key < Tkey;
      }
    }
    {
      unsigned long long m = __ballot(cpass);
      if (m){
        int pc = __popcll(m);
        if (ccnt + pc > CAPC){
          Tkey = compact_cost(cbuf, ccnt); ccnt = TOPK_;
          float Tc = unfkey((unsigned int)(Tkey >> 32));
          tc48 = Tc < 48.0f;                        // iou=0 => cost > 48.35
          float gt_ = 3.02f + log10f(Tc);           // +0.02 conservative margin
          gthr2 = (gt_ > 0.0f) ? gt_*gt_ : 1e30f;
        }
        int pos = ccnt + (int)__popcll(m & ((1ull << lane) - 1ull));
        if (cpass) cbuf[pos] = key;
        ccnt += pc;
      }
    }
  }

  // final per-wave exact selection, then cross-wave merge
  compact_cost(cbuf, ccnt);
  compact_iou(ibuf, icnt);
  if (lane < TOPK_){ s_fk[wid][lane] = cbuf[lane]; s_fi[wid][lane] = ibuf[lane]; }
  if (lane == TOPK_){ s_fk[wid][TOPK_] = ~0ull; s_fi[wid][TOPK_] = -1e30f; }
  __syncthreads();

  if (tid == 0){
    // merge 4 descending iou lists; sum top-13 in descending order
    int p0 = 0, p1 = 0, p2 = 0, p3 = 0; float s = 0.0f;
    for (int r = 0; r < TOPK_; ++r){
      float v0 = s_fi[0][p0], v1 = s_fi[1][p1], v2 = s_fi[2][p2], v3 = s_fi[3][p3];
      float mx = fmaxf(fmaxf(v0, v1), fmaxf(v2, v3));
      if      (v0 == mx) p0++;
      else if (v1 == mx) p1++;
      else if (v2 == mx) p2++;
      else               p3++;
      s += fmaxf(mx, 0.0f);                        // sentinels add 0
    }
    int dynk = (int)s;                             // trunc toward zero
    if (dynk < 1) dynk = 1;
    if (dynk > TOPK_) dynk = TOPK_;
    // merge 4 ascending key lists; scatter first dynk
    int q0 = 0, q1 = 0, q2 = 0, q3 = 0;
    for (int r = 0; r < dynk; ++r){
      unsigned long long k0 = s_fk[0][q0], k1 = s_fk[1][q1];
      unsigned long long k2 = s_fk[2][q2], k3 = s_fk[3][q3];
      unsigned long long mn = k0 < k1 ? k0 : k1;
      unsigned long long mn2 = k2 < k3 ? k2 : k3;
      mn = mn < mn2 ? mn : mn2;
      if      (k0 == mn) q0++;
      else if (k1 == mn) q1++;
      else if (k2 == mn) q2++;
      else               q3++;
      int n = (int)(mn & 0xffffffffu);
      atomicOr(&match_mask[((size_t)b*N_ + n)*4 + (g >> 5)], 1u << (g & 31));
    }
  }
}

// ---------- kernel 2: per (b,n) final assignment ----------
// fast path count<=1; count>1 resolved wave-cooperatively (g across lanes)

__global__ void __launch_bounds__(BDIM) k_assign(
    const float* __restrict__ pred_bboxes,
    const float* __restrict__ pred_scores,
    const float* __restrict__ priors,
    const int*   __restrict__ gt_labels,
    const float* __restrict__ gt_bboxes,
    const unsigned char* __restrict__ valid_mask,
    const uint32_t* __restrict__ match_mask,
    float* __restrict__ out)
{
  #pragma clang fp contract(off)
  const int b = blockIdx.y;
  __shared__ float4 sbox[G_];
  __shared__ int    slbl[G_];
  __shared__ float  sga[G_], sgcx[G_], sgcy[G_];
  for (int g = threadIdx.x; g < G_; g += BDIM){
    float4 q = ((const float4*)gt_bboxes)[b*G_ + g];
    sbox[g] = q; slbl[g] = gt_labels[b*G_ + g];
    sga[g]  = (q.z - q.x) * (q.w - q.y);
    sgcx[g] = (q.x + q.z) * 0.5f;
    sgcy[g] = (q.y + q.w) * 0.5f;
  }
  __syncthreads();
  int n = blockIdx.x*BDIM + threadIdx.x;
  if (n >= N_) return;                 // N_ is a multiple of 64: wave-aligned exit
  const int lane = threadIdx.x & 63;
  size_t idx = (size_t)b*N_ + n;
  uint4 mm = ((const uint4*)match_mask)[idx];
  int count = __popc(mm.x) + __popc(mm.y) + __popc(mm.z) + __popc(mm.w);

  float lblv = (float)NCLS;
  float4 ob = make_float4(0.f, 0.f, 0.f, 0.f);
  float met = 0.0f;

  if (__any(count > 0)){
    float4 pb = make_float4(0.f,0.f,0.f,0.f); float pa = 0.0f;
    if (count > 0){
      pb = ((const float4*)pred_bboxes)[idx];
      pa = (pb.z - pb.x) * (pb.w - pb.y);
    }
    if (count == 1){
      int mg = mm.x ? (__ffs(mm.x) - 1) :
               mm.y ? (31 + __ffs(mm.y)) :
               mm.z ? (63 + __ffs(mm.z)) : (95 + __ffs(mm.w));
      float4 q = sbox[mg];
      float lx = fmaxf(pb.x, q.x), ly = fmaxf(pb.y, q.y);
      float rx = fminf(pb.z, q.z), ry = fminf(pb.w, q.w);
      float ov = fmaxf(rx - lx, 0.0f) * fmaxf(ry - ly, 0.0f);
      float iou = ov / fmaxf(pa + sga[mg] - ov, 1e-6f);
      lblv = (float)slbl[mg]; ob = q; met = iou;
    }
    unsigned long long heavy = __ballot(count > 1);
    if (heavy){
      float4 pr = make_float4(0.f,0.f,0.f,0.f); int hv0 = 0;
      if (count > 1){
        pr = ((const float4*)priors)[n];
        hv0 = valid_mask[idx];
      }
      while (heavy){
        int src = (int)(__ffsll((unsigned long long)heavy) - 1);
        heavy &= heavy - 1ull;
        // broadcast the heavy anchor
        float hx1 = __shfl(pb.x, src, 64), hy1 = __shfl(pb.y, src, 64);
        float hx2 = __shfl(pb.z, src, 64), hy2 = __shfl(pb.w, src, 64);
        float hpa = __shfl(pa,   src, 64);
        float hcx = __shfl(pr.x, src, 64), hcy = __shfl(pr.y, src, 64);
        float hst = __shfl(pr.z, src, 64);
        int   hv  = __shfl(hv0,  src, 64);
        int   hn  = __shfl(n,    src, 64);
        float hinvs = __uint_as_float(0x7F000000u - __float_as_uint(hst));
        const float* hrow = pred_scores + ((size_t)b*N_ + hn)*(size_t)NCLS;

        unsigned long long bk = ~0ull;
        #pragma unroll
        for (int h = 0; h < 2; ++h){
          int g = lane + h*64;
          if (g < G_){
            float4 q = sbox[g];
            float lx = fmaxf(hx1, q.x), ly = fmaxf(hy1, q.y);
            float rx = fminf(hx2, q.z), ry = fminf(hy2, q.w);
            float ov = fmaxf(rx - lx, 0.0f) * fmaxf(ry - ly, 0.0f);
            float un = hpa + sga[g] - ov;
            float iou = ov / fmaxf(un, 1e-6f);
            float dx = hcx - sgcx[g], dy = hcy - sgcy[g];
            float dist = sqrtf(dx*dx + dy*dy) * hinvs;
            float x = hrow[slbl[g]];
            float c = cost_eval(iou, x, dist, hv != 0);
            unsigned long long key = ((unsigned long long)fkey(c) << 32) | (unsigned)g;
            bk = key < bk ? key : bk;
          }
        }
        // 64-lane min reduce (cost ties -> smaller g, matches jnp.argmin)
        #pragma unroll
        for (int m = 1; m < 64; m <<= 1){
          unsigned int lo = (unsigned int)__shfl_xor((int)(unsigned int)bk, m, 64);
          unsigned int hi = (unsigned int)__shfl_xor((int)(unsigned int)(bk >> 32), m, 64);
          unsigned long long o = ((unsigned long long)hi << 32) | lo;
          bk = o < bk ? o : bk;
        }
        if (lane == src){
          int gw = (int)(bk & 0xffffffffu);
          float4 q = sbox[gw];
          float lx = fmaxf(pb.x, q.x), ly = fmaxf(pb.y, q.y);
          float rx = fminf(pb.z, q.z), ry = fminf(pb.w, q.w);
          float ov = fmaxf(rx - lx, 0.0f) * fmaxf(ry - ly, 0.0f);
          met  = ov / fmaxf(pa + sga[gw] - ov, 1e-6f);
          lblv = (float)slbl[gw];
          ob = q;
        }
      }
    }
  }

  out[idx] = lblv;                                   // assigned_labels
  out[(size_t)B_*N_ + idx] = 1.0f;                   // weights
  ((float4*)(out + (size_t)2*B_*N_))[idx] = ob;      // assigned_bboxes
  out[(size_t)6*B_*N_ + idx] = met;                  // assign_metrics
}

// ---------- launch ----------

extern "C" void kernel_launch(void* const* d_in, const int* in_sizes, int n_in,
                              void* d_out, int out_size, void* d_ws, size_t ws_size,
                              hipStream_t stream) {
  const float* pred_bboxes = (const float*)d_in[0];
  const float* pred_scores = (const float*)d_in[1];
  const float* priors      = (const float*)d_in[2];
  const int*   gt_labels   = (const int*)  d_in[3];
  const float* gt_bboxes   = (const float*)d_in[4];
  const float* pad_flag    = (const float*)d_in[5];
  float* out = (float*)d_out;

  // ws layout: match bitmask (B*N*4 u32 = 4,300,800 B) | valid mask (B*N bytes)
  const size_t MASK_B = (size_t)B_*N_*4*sizeof(uint32_t);
  uint32_t* match_mask = (uint32_t*)d_ws;
  unsigned char* valid_mask = (unsigned char*)d_ws + MASK_B;

  dim3 gridN((N_ + BDIM - 1)/BDIM, B_);
  dim3 gridG(G_, B_);

  k_validmask<<<gridN, BDIM, 0, stream>>>(priors, gt_bboxes, pad_flag,
                                          valid_mask, match_mask);
  k_topk<<<gridG, BDIM, 0, stream>>>(pred_bboxes, pred_scores, priors, gt_labels,
                                     gt_bboxes, pad_flag, valid_mask, match_mask);
  k_assign<<<gridN, BDIM, 0, stream>>>(pred_bboxes, pred_scores, priors, gt_labels,
                                       gt_bboxes, valid_mask, match_mask, out);
}

// Round 5
// 139.446 us; speedup vs baseline: 4.7855x; 1.0110x over previous
//
#include <hip/hip_runtime.h>
#include <stdint.h>

#define BDIM 256
#define B_   8
#define NCLS 80
#define G_   100
#define N_   33600
#define TOPK_ 13
#define NCHUNK 4
#define NCSZ (N_/NCHUNK)   // 8400
#define CAPC 160     // per-wave cost candidate buffer (u64 keys)
#define CAPI 160     // per-wave iou candidate buffer (f32)
#define INFC 1e8f

// ---------- helpers ----------

__device__ __forceinline__ unsigned int fkey(float f){
  unsigned int u = __float_as_uint(f);
  return (u & 0x80000000u) ? ~u : (u | 0x80000000u);  // monotonic float->uint
}
__device__ __forceinline__ float unfkey(unsigned int k){
  unsigned int u = (k & 0x80000000u) ? (k & 0x7fffffffu) : ~k;
  return __uint_as_float(u);
}

// cost = bce*(scale^2) + (-log(iou+eps)*3) + 10^(dist-3); INF-masked by valid
__device__ __forceinline__ float cost_eval(float iou, float x, float dist, bool valid){
  #pragma clang fp contract(off)
  float prior = exp2f((dist - 3.0f) * 3.321928094887362f);   // 10^(dist-3)
  float iouc  = -logf(iou + 1e-7f) * 3.0f;
  float sig   = 1.0f / (1.0f + expf(-x));
  float sc    = iou - sig;
  float bce   = fmaxf(x, 0.0f) + log1pf(expf(-fabsf(x))) - x * iou;
  float c     = bce * (sc * sc) + iouc + prior;
  return valid ? c : INFC;
}

// exact selection of 13 smallest u64 keys from buf[0..cnt) (cnt<=CAPC<=192).
__device__ unsigned long long compact_cost(unsigned long long* buf, int cnt){
  const int lane = threadIdx.x & 63;
  unsigned long long a0 = (lane       < cnt) ? buf[lane]       : ~0ull;
  unsigned long long a1 = (lane + 64  < cnt) ? buf[lane + 64]  : ~0ull;
  unsigned long long a2 = (lane + 128 < cnt) ? buf[lane + 128] : ~0ull;
  unsigned long long mykeep = ~0ull, t13 = ~0ull;
  #pragma unroll
  for (int r = 0; r < TOPK_; ++r){
    unsigned long long v = a0 < a1 ? a0 : a1; v = v < a2 ? v : a2;
    unsigned long long mn = v;
    #pragma unroll
    for (int m = 1; m < 64; m <<= 1){
      unsigned int lo = (unsigned int)__shfl_xor((int)(unsigned int)mn, m, 64);
      unsigned int hi = (unsigned int)__shfl_xor((int)(unsigned int)(mn >> 32), m, 64);
      unsigned long long o = ((unsigned long long)hi << 32) | lo;
      mn = o < mn ? o : mn;
    }
    if      (a0 == mn) a0 = ~0ull;   // keys unique: exactly one real slot matches
    else if (a1 == mn) a1 = ~0ull;
    else if (a2 == mn) a2 = ~0ull;
    if (lane == r) mykeep = mn;
    t13 = mn;
  }
  if (lane < TOPK_) buf[lane] = mykeep;
  return t13;
}

// exact selection of 13 largest floats (dups allowed) from buf[0..cnt).
__device__ float compact_iou(float* buf, int cnt){
  const int lane = threadIdx.x & 63;
  float a0 = (lane       < cnt) ? buf[lane]       : -1.0f;
  float a1 = (lane + 64  < cnt) ? buf[lane + 64]  : -1.0f;
  float a2 = (lane + 128 < cnt) ? buf[lane + 128] : -1.0f;
  float mykeep = -1.0f, t13 = -1.0f;
  #pragma unroll
  for (int r = 0; r < TOPK_; ++r){
    float mx = fmaxf(fmaxf(a0, a1), a2);
    #pragma unroll
    for (int m = 1; m < 64; m <<= 1) mx = fmaxf(mx, __shfl_xor(mx, m, 64));
    bool h0 = (a0 == mx), h1 = (a1 == mx), h2 = (a2 == mx);
    unsigned long long ball = __ballot(h0 | h1 | h2);
    int src = (int)(__ffsll(ball) - 1);
    if (lane == src){                      // clear exactly one instance
      if (h0) a0 = -1.0f; else if (h1) a1 = -1.0f; else a2 = -1.0f;
    }
    if (lane == r) mykeep = mx;
    t13 = mx;
  }
  if (lane < TOPK_) buf[lane] = mykeep;
  return t13;
}

// ---------- kernel 0: valid mask + zero bitmask ----------

__global__ void __launch_bounds__(BDIM) k_validmask(
    const float* __restrict__ priors,
    const float* __restrict__ gt_bboxes,
    const float* __restrict__ pad_flag,
    unsigned char* __restrict__ valid_mask,
    uint32_t* __restrict__ match_mask)
{
  int b = blockIdx.y;
  __shared__ float4 sbox[G_];
  __shared__ float  sflag[G_];
  for (int g = threadIdx.x; g < G_; g += BDIM){
    sbox[g]  = ((const float4*)gt_bboxes)[b*G_ + g];
    sflag[g] = pad_flag[b*G_ + g];
  }
  __syncthreads();
  int n = blockIdx.x*BDIM + threadIdx.x;
  if (n >= N_) return;
  float cx = priors[n*4+0], cy = priors[n*4+1];
  bool v = false;
  for (int g = 0; g < G_; ++g){
    float4 gb = sbox[g];
    bool in = (cx - gb.x > 0.0f) & (cy - gb.y > 0.0f) &
              (gb.z - cx > 0.0f) & (gb.w - cy > 0.0f) & (sflag[g] > 0.0f);
    v |= in;
  }
  size_t idx = (size_t)b*N_ + n;
  valid_mask[idx] = v ? 1 : 0;
  ((uint4*)match_mask)[idx] = make_uint4(0u,0u,0u,0u);
}

// ---------- kernel 1: per (b,g,chunk) wave-cooperative streaming top-13 ----------

__global__ void __launch_bounds__(BDIM) k_topk(
    const float* __restrict__ pred_bboxes,
    const float* __restrict__ pred_scores,
    const float* __restrict__ priors,
    const int*   __restrict__ gt_labels,
    const float* __restrict__ gt_bboxes,
    const float* __restrict__ pad_flag,
    const unsigned char* __restrict__ valid_mask,
    unsigned long long* __restrict__ ck_out,
    float* __restrict__ ci_out)
{
  #pragma clang fp contract(off)
  const int g = blockIdx.x, b = blockIdx.y, chunk = blockIdx.z;
  if (pad_flag[b*G_ + g] <= 0.0f) return;   // invalid gt: no matches

  __shared__ unsigned long long s_cbuf[4][CAPC];
  __shared__ float s_ibuf[4][CAPI];
  __shared__ unsigned long long s_fk[4][TOPK_ + 1];
  __shared__ float s_fi[4][TOPK_ + 1];

  const int tid = threadIdx.x, lane = tid & 63, wid = tid >> 6;
  unsigned long long* cbuf = s_cbuf[wid];
  float* ibuf = s_ibuf[wid];

  const float4 gb = ((const float4*)gt_bboxes)[b*G_ + g];
  const float ga  = (gb.z - gb.x) * (gb.w - gb.y);
  const float gcx = (gb.x + gb.z) * 0.5f, gcy = (gb.y + gb.w) * 0.5f;
  const int lbl = gt_labels[b*G_ + g];
  const unsigned int KEYINF = fkey(INFC);

  // running thresholds (wave-uniform registers)
  unsigned long long Tkey = ~0ull;   // exact 13th-smallest (cost,idx) key so far
  bool  tc48  = false;               // Tc < 48 => iou==0 anchors provably out
  float gthr2 = 1e30f;               // (3+log10(Tc)+0.02)^2 dist-gate (strides^2)
  float Tiou_m = 0.0f;               // conservative iou gate threshold
  int ccnt = 0, icnt = 0;

  const float4* pb4 = (const float4*)pred_bboxes + (size_t)b*N_;
  const float4* pr4 = (const float4*)priors;
  const unsigned char* vm = valid_mask + (size_t)b*N_;
  const float* sc_b = pred_scores + (size_t)b*N_*NCLS;

  const int nend = (chunk + 1) * NCSZ;
  for (int n = chunk*NCSZ + tid; n < nend; n += BDIM){
    float4 pb = pb4[n];
    float4 pr = pr4[n];
    float pa = (pb.z - pb.x) * (pb.w - pb.y);
    float lx = fmaxf(pb.x, gb.x), ly = fmaxf(pb.y, gb.y);
    float rx = fminf(pb.z, gb.z), ry = fminf(pb.w, gb.w);
    float ov = fmaxf(rx - lx, 0.0f) * fmaxf(ry - ly, 0.0f);
    float un = pa + ga - ov;                      // un >= max(pa,ga) > 0
    bool ipass = ov > Tiou_m * un;                // superset of {iou > Tiou}

    float invs = __uint_as_float(0x7F000000u - __float_as_uint(pr.z)); // exact 1/2^k
    float dx = pr.x - gcx, dy = pr.y - gcy;
    float dist2 = dx*dx + dy*dy;
    float d2s = dist2 * (invs * invs);
    bool valid = vm[n] != 0;
    // conservative: skip iff provably cost > Tc
    bool needcost = valid && (d2s <= gthr2) && !((ov <= 0.0f) && tc48);

    float iou = 0.0f;
    if (__any(ipass || needcost)){
      if (ipass || needcost) iou = ov / fmaxf(un, 1e-6f);
    }

    // ---- iou top-13 stream (values only; sum feeds dyn_k) ----
    {
      unsigned long long m = __ballot(ipass);
      if (m){
        int pc = __popcll(m);
        if (icnt + pc > CAPI){
          float t = compact_iou(ibuf, icnt); icnt = TOPK_;
          Tiou_m = t * 0.999f;                     // conservative down
        }
        int pos = icnt + (int)__popcll(m & ((1ull << lane) - 1ull));
        if (ipass) ibuf[pos] = iou;
        icnt += pc;
      }
    }

    // ---- cost top-13 stream ----
    unsigned long long key = ((unsigned long long)KEYINF << 32) | (unsigned)n;
    bool cpass = (!valid) && (key < Tkey);         // invalid: cost == 1e8 exactly
    if (__any(needcost)){
      if (needcost){
        float x = sc_b[(size_t)n*NCLS + lbl];
        float dist = sqrtf(dist2) * invs;          // == sqrt(d2)/stride exactly
        float c = cost_eval(iou, x, dist, true);
        key = ((unsigned long long)fkey(c) << 32) | (unsigned)n;
        cpass = key < Tkey;
      }
    }
    {
      unsigned long long m = __ballot(cpass);
      if (m){
        int pc = __popcll(m);
        if (ccnt + pc > CAPC){
          Tkey = compact_cost(cbuf, ccnt); ccnt = TOPK_;
          float Tc = unfkey((unsigned int)(Tkey >> 32));
          tc48 = Tc < 48.0f;                        // iou=0 => cost > 48.35
          float gt_ = 3.02f + log10f(Tc);           // +0.02 conservative margin
          gthr2 = (gt_ > 0.0f) ? gt_*gt_ : 1e30f;
        }
        int pos = ccnt + (int)__popcll(m & ((1ull << lane) - 1ull));
        if (cpass) cbuf[pos] = key;
        ccnt += pc;
      }
    }
  }

  // final per-wave exact selection, then cross-wave merge -> chunk result
  compact_cost(cbuf, ccnt);
  compact_iou(ibuf, icnt);
  if (lane < TOPK_){ s_fk[wid][lane] = cbuf[lane]; s_fi[wid][lane] = ibuf[lane]; }
  if (lane == TOPK_){ s_fk[wid][TOPK_] = ~0ull; s_fi[wid][TOPK_] = -1e30f; }
  __syncthreads();

  if (tid == 0){
    size_t base = (((size_t)b*G_ + g)*NCHUNK + chunk)*TOPK_;
    // merge 4 descending iou lists -> 13 descending
    {
      int p0 = 0, p1 = 0, p2 = 0, p3 = 0;
      for (int r = 0; r < TOPK_; ++r){
        float v0 = s_fi[0][p0], v1 = s_fi[1][p1], v2 = s_fi[2][p2], v3 = s_fi[3][p3];
        float mx = fmaxf(fmaxf(v0, v1), fmaxf(v2, v3));
        if      (v0 == mx) p0++;
        else if (v1 == mx) p1++;
        else if (v2 == mx) p2++;
        else               p3++;
        ci_out[base + r] = mx;
      }
    }
    // merge 4 ascending key lists -> 13 ascending
    {
      int q0 = 0, q1 = 0, q2 = 0, q3 = 0;
      for (int r = 0; r < TOPK_; ++r){
        unsigned long long k0 = s_fk[0][q0], k1 = s_fk[1][q1];
        unsigned long long k2 = s_fk[2][q2], k3 = s_fk[3][q3];
        unsigned long long mn = k0 < k1 ? k0 : k1;
        unsigned long long mn2 = k2 < k3 ? k2 : k3;
        mn = mn < mn2 ? mn : mn2;
        if      (k0 == mn) q0++;
        else if (k1 == mn) q1++;
        else if (k2 == mn) q2++;
        else               q3++;
        ck_out[base + r] = mn;
      }
    }
  }
}

// ---------- kernel 1b: merge NCHUNK chunk results, compute dyn_k, scatter ----------

__global__ void __launch_bounds__(64) k_merge(
    const float* __restrict__ pad_flag,
    const unsigned long long* __restrict__ ck,
    const float* __restrict__ ci,
    uint32_t* __restrict__ match_mask)
{
  const int g = blockIdx.x, b = blockIdx.y;
  if (threadIdx.x != 0) return;
  if (pad_flag[b*G_ + g] <= 0.0f) return;

  const size_t base = ((size_t)b*G_ + g)*NCHUNK*TOPK_;
  const unsigned long long* K = ck + base;
  const float* I = ci + base;

  // merge 4 descending iou lists; sum top-13 in descending order
  int p0 = 0, p1 = 0, p2 = 0, p3 = 0; float s = 0.0f;
  for (int r = 0; r < TOPK_; ++r){
    float v0 = (p0 < TOPK_) ? I[0*TOPK_ + p0] : -1e30f;
    float v1 = (p1 < TOPK_) ? I[1*TOPK_ + p1] : -1e30f;
    float v2 = (p2 < TOPK_) ? I[2*TOPK_ + p2] : -1e30f;
    float v3 = (p3 < TOPK_) ? I[3*TOPK_ + p3] : -1e30f;
    float mx = fmaxf(fmaxf(v0, v1), fmaxf(v2, v3));
    if      (v0 == mx) p0++;
    else if (v1 == mx) p1++;
    else if (v2 == mx) p2++;
    else               p3++;
    s += fmaxf(mx, 0.0f);                        // sentinels add 0
  }
  int dynk = (int)s;                             // trunc toward zero
  if (dynk < 1) dynk = 1;
  if (dynk > TOPK_) dynk = TOPK_;

  // merge 4 ascending key lists; scatter first dynk
  int q0 = 0, q1 = 0, q2 = 0, q3 = 0;
  for (int r = 0; r < dynk; ++r){
    unsigned long long k0 = (q0 < TOPK_) ? K[0*TOPK_ + q0] : ~0ull;
    unsigned long long k1 = (q1 < TOPK_) ? K[1*TOPK_ + q1] : ~0ull;
    unsigned long long k2 = (q2 < TOPK_) ? K[2*TOPK_ + q2] : ~0ull;
    unsigned long long k3 = (q3 < TOPK_) ? K[3*TOPK_ + q3] : ~0ull;
    unsigned long long mn = k0 < k1 ? k0 : k1;
    unsigned long long mn2 = k2 < k3 ? k2 : k3;
    mn = mn < mn2 ? mn : mn2;
    if      (k0 == mn) q0++;
    else if (k1 == mn) q1++;
    else if (k2 == mn) q2++;
    else               q3++;
    int n = (int)(mn & 0xffffffffu);
    atomicOr(&match_mask[((size_t)b*N_ + n)*4 + (g >> 5)], 1u << (g & 31));
  }
}

// ---------- kernel 2: per (b,n) final assignment ----------
// fast path count<=1; count>1 resolved wave-cooperatively (g across lanes)

__global__ void __launch_bounds__(BDIM) k_assign(
    const float* __restrict__ pred_bboxes,
    const float* __restrict__ pred_scores,
    const float* __restrict__ priors,
    const int*   __restrict__ gt_labels,
    const float* __restrict__ gt_bboxes,
    const unsigned char* __restrict__ valid_mask,
    const uint32_t* __restrict__ match_mask,
    float* __restrict__ out)
{
  #pragma clang fp contract(off)
  const int b = blockIdx.y;
  __shared__ float4 sbox[G_];
  __shared__ int    slbl[G_];
  __shared__ float  sga[G_], sgcx[G_], sgcy[G_];
  for (int g = threadIdx.x; g < G_; g += BDIM){
    float4 q = ((const float4*)gt_bboxes)[b*G_ + g];
    sbox[g] = q; slbl[g] = gt_labels[b*G_ + g];
    sga[g]  = (q.z - q.x) * (q.w - q.y);
    sgcx[g] = (q.x + q.z) * 0.5f;
    sgcy[g] = (q.y + q.w) * 0.5f;
  }
  __syncthreads();
  int n = blockIdx.x*BDIM + threadIdx.x;
  if (n >= N_) return;                 // N_ is a multiple of 64: wave-aligned exit
  const int lane = threadIdx.x & 63;
  size_t idx = (size_t)b*N_ + n;
  uint4 mm = ((const uint4*)match_mask)[idx];
  int count = __popc(mm.x) + __popc(mm.y) + __popc(mm.z) + __popc(mm.w);

  float lblv = (float)NCLS;
  float4 ob = make_float4(0.f, 0.f, 0.f, 0.f);
  float met = 0.0f;

  if (__any(count > 0)){
    float4 pb = make_float4(0.f,0.f,0.f,0.f); float pa = 0.0f;
    if (count > 0){
      pb = ((const float4*)pred_bboxes)[idx];
      pa = (pb.z - pb.x) * (pb.w - pb.y);
    }
    if (count == 1){
      int mg = mm.x ? (__ffs(mm.x) - 1) :
               mm.y ? (31 + __ffs(mm.y)) :
               mm.z ? (63 + __ffs(mm.z)) : (95 + __ffs(mm.w));
      float4 q = sbox[mg];
      float lx = fmaxf(pb.x, q.x), ly = fmaxf(pb.y, q.y);
      float rx = fminf(pb.z, q.z), ry = fminf(pb.w, q.w);
      float ov = fmaxf(rx - lx, 0.0f) * fmaxf(ry - ly, 0.0f);
      float iou = ov / fmaxf(pa + sga[mg] - ov, 1e-6f);
      lblv = (float)slbl[mg]; ob = q; met = iou;
    }
    unsigned long long heavy = __ballot(count > 1);
    if (heavy){
      float4 pr = make_float4(0.f,0.f,0.f,0.f); int hv0 = 0;
      if (count > 1){
        pr = ((const float4*)priors)[n];
        hv0 = valid_mask[idx];
      }
      while (heavy){
        int src = (int)(__ffsll((unsigned long long)heavy) - 1);
        heavy &= heavy - 1ull;
        // broadcast the heavy anchor
        float hx1 = __shfl(pb.x, src, 64), hy1 = __shfl(pb.y, src, 64);
        float hx2 = __shfl(pb.z, src, 64), hy2 = __shfl(pb.w, src, 64);
        float hpa = __shfl(pa,   src, 64);
        float hcx = __shfl(pr.x, src, 64), hcy = __shfl(pr.y, src, 64);
        float hst = __shfl(pr.z, src, 64);
        int   hv  = __shfl(hv0,  src, 64);
        int   hn  = __shfl(n,    src, 64);
        float hinvs = __uint_as_float(0x7F000000u - __float_as_uint(hst));
        const float* hrow = pred_scores + ((size_t)b*N_ + hn)*(size_t)NCLS;

        unsigned long long bk = ~0ull;
        #pragma unroll
        for (int h = 0; h < 2; ++h){
          int g = lane + h*64;
          if (g < G_){
            float4 q = sbox[g];
            float lx = fmaxf(hx1, q.x), ly = fmaxf(hy1, q.y);
            float rx = fminf(hx2, q.z), ry = fminf(hy2, q.w);
            float ov = fmaxf(rx - lx, 0.0f) * fmaxf(ry - ly, 0.0f);
            float un = hpa + sga[g] - ov;
            float iou = ov / fmaxf(un, 1e-6f);
            float dx = hcx - sgcx[g], dy = hcy - sgcy[g];
            float dist = sqrtf(dx*dx + dy*dy) * hinvs;
            float x = hrow[slbl[g]];
            float c = cost_eval(iou, x, dist, hv != 0);
            unsigned long long key = ((unsigned long long)fkey(c) << 32) | (unsigned)g;
            bk = key < bk ? key : bk;
          }
        }
        // 64-lane min reduce (cost ties -> smaller g, matches jnp.argmin)
        #pragma unroll
        for (int m = 1; m < 64; m <<= 1){
          unsigned int lo = (unsigned int)__shfl_xor((int)(unsigned int)bk, m, 64);
          unsigned int hi = (unsigned int)__shfl_xor((int)(unsigned int)(bk >> 32), m, 64);
          unsigned long long o = ((unsigned long long)hi << 32) | lo;
          bk = o < bk ? o : bk;
        }
        if (lane == src){
          int gw = (int)(bk & 0xffffffffu);
          float4 q = sbox[gw];
          float lx = fmaxf(pb.x, q.x), ly = fmaxf(pb.y, q.y);
          float rx = fminf(pb.z, q.z), ry = fminf(pb.w, q.w);
          float ov = fmaxf(rx - lx, 0.0f) * fmaxf(ry - ly, 0.0f);
          met  = ov / fmaxf(pa + sga[gw] - ov, 1e-6f);
          lblv = (float)slbl[gw];
          ob = q;
        }
      }
    }
  }

  out[idx] = lblv;                                   // assigned_labels
  out[(size_t)B_*N_ + idx] = 1.0f;                   // weights
  ((float4*)(out + (size_t)2*B_*N_))[idx] = ob;      // assigned_bboxes
  out[(size_t)6*B_*N_ + idx] = met;                  // assign_metrics
}

// ---------- launch ----------

extern "C" void kernel_launch(void* const* d_in, const int* in_sizes, int n_in,
                              void* d_out, int out_size, void* d_ws, size_t ws_size,
                              hipStream_t stream) {
  const float* pred_bboxes = (const float*)d_in[0];
  const float* pred_scores = (const float*)d_in[1];
  const float* priors      = (const float*)d_in[2];
  const int*   gt_labels   = (const int*)  d_in[3];
  const float* gt_bboxes   = (const float*)d_in[4];
  const float* pad_flag    = (const float*)d_in[5];
  float* out = (float*)d_out;

  // ws layout: match bitmask | valid mask | chunk keys | chunk ious
  const size_t MASK_B  = (size_t)B_*N_*4*sizeof(uint32_t);               // 4,300,800
  const size_t VALID_B = ((size_t)B_*N_ + 255) & ~(size_t)255;           //   268,800
  const size_t CK_B    = (size_t)B_*G_*NCHUNK*TOPK_*sizeof(unsigned long long); // 332,800
  uint32_t* match_mask = (uint32_t*)d_ws;
  unsigned char* valid_mask = (unsigned char*)d_ws + MASK_B;
  unsigned long long* ck = (unsigned long long*)((char*)d_ws + MASK_B + VALID_B);
  float* ci = (float*)((char*)d_ws + MASK_B + VALID_B + CK_B);

  dim3 gridN((N_ + BDIM - 1)/BDIM, B_);
  dim3 gridG(G_, B_, NCHUNK);
  dim3 gridM(G_, B_);

  k_validmask<<<gridN, BDIM, 0, stream>>>(priors, gt_bboxes, pad_flag,
                                          valid_mask, match_mask);
  k_topk<<<gridG, BDIM, 0, stream>>>(pred_bboxes, pred_scores, priors, gt_labels,
                                     gt_bboxes, pad_flag, valid_mask, ck, ci);
  k_merge<<<gridM, 64, 0, stream>>>(pad_flag, ck, ci, match_mask);
  k_assign<<<gridN, BDIM, 0, stream>>>(pred_bboxes, pred_scores, priors, gt_labels,
                                       gt_bboxes, valid_mask, match_mask, out);
}

// Round 6
// 131.366 us; speedup vs baseline: 5.0799x; 1.0615x over previous
//
#include <hip/hip_runtime.h>
#include <stdint.h>

#define BDIM 256
#define B_   8
#define NCLS 80
#define G_   100
#define N_   33600
#define TOPK_ 13
#define NCHUNK 4
#define NCSZ (N_/NCHUNK)   // 8400
#define CAPC 160     // per-wave cost candidate buffer (u64 keys)
#define CAPI 160     // per-wave iou candidate buffer (f32)
#define INFC 1e8f

// ---------- helpers ----------

__device__ __forceinline__ unsigned int fkey(float f){
  unsigned int u = __float_as_uint(f);
  return (u & 0x80000000u) ? ~u : (u | 0x80000000u);  // monotonic float->uint
}
__device__ __forceinline__ float unfkey(unsigned int k){
  unsigned int u = (k & 0x80000000u) ? (k & 0x7fffffffu) : ~k;
  return __uint_as_float(u);
}

// cost = bce*(scale^2) + (-log(iou+eps)*3) + 10^(dist-3); INF-masked by valid
__device__ __forceinline__ float cost_eval(float iou, float x, float dist, bool valid){
  #pragma clang fp contract(off)
  float prior = exp2f((dist - 3.0f) * 3.321928094887362f);   // 10^(dist-3)
  float iouc  = -logf(iou + 1e-7f) * 3.0f;
  float sig   = 1.0f / (1.0f + expf(-x));
  float sc    = iou - sig;
  float bce   = fmaxf(x, 0.0f) + log1pf(expf(-fabsf(x))) - x * iou;
  float c     = bce * (sc * sc) + iouc + prior;
  return valid ? c : INFC;
}

__device__ __forceinline__ unsigned long long wave_min_u64(unsigned long long v){
  #pragma unroll
  for (int m = 1; m < 64; m <<= 1){
    unsigned int lo = (unsigned int)__shfl_xor((int)(unsigned int)v, m, 64);
    unsigned int hi = (unsigned int)__shfl_xor((int)(unsigned int)(v >> 32), m, 64);
    unsigned long long o = ((unsigned long long)hi << 32) | lo;
    v = o < v ? o : v;
  }
  return v;
}

// exact selection of 13 smallest u64 keys from buf[0..cnt) (cnt<=CAPC<=192).
__device__ unsigned long long compact_cost(unsigned long long* buf, int cnt){
  const int lane = threadIdx.x & 63;
  unsigned long long a0 = (lane       < cnt) ? buf[lane]       : ~0ull;
  unsigned long long a1 = (lane + 64  < cnt) ? buf[lane + 64]  : ~0ull;
  unsigned long long a2 = (lane + 128 < cnt) ? buf[lane + 128] : ~0ull;
  unsigned long long mykeep = ~0ull, t13 = ~0ull;
  #pragma unroll
  for (int r = 0; r < TOPK_; ++r){
    unsigned long long v = a0 < a1 ? a0 : a1; v = v < a2 ? v : a2;
    unsigned long long mn = wave_min_u64(v);
    if      (a0 == mn) a0 = ~0ull;   // keys unique: exactly one real slot matches
    else if (a1 == mn) a1 = ~0ull;
    else if (a2 == mn) a2 = ~0ull;
    if (lane == r) mykeep = mn;
    t13 = mn;
  }
  if (lane < TOPK_) buf[lane] = mykeep;
  return t13;
}

// exact selection of 13 largest floats (dups allowed) from buf[0..cnt).
__device__ float compact_iou(float* buf, int cnt){
  const int lane = threadIdx.x & 63;
  float a0 = (lane       < cnt) ? buf[lane]       : -1.0f;
  float a1 = (lane + 64  < cnt) ? buf[lane + 64]  : -1.0f;
  float a2 = (lane + 128 < cnt) ? buf[lane + 128] : -1.0f;
  float mykeep = -1.0f, t13 = -1.0f;
  #pragma unroll
  for (int r = 0; r < TOPK_; ++r){
    float mx = fmaxf(fmaxf(a0, a1), a2);
    #pragma unroll
    for (int m = 1; m < 64; m <<= 1) mx = fmaxf(mx, __shfl_xor(mx, m, 64));
    bool h0 = (a0 == mx), h1 = (a1 == mx), h2 = (a2 == mx);
    unsigned long long ball = __ballot(h0 | h1 | h2);
    int src = (int)(__ffsll(ball) - 1);
    if (lane == src){                      // clear exactly one instance
      if (h0) a0 = -1.0f; else if (h1) a1 = -1.0f; else a2 = -1.0f;
    }
    if (lane == r) mykeep = mx;
    t13 = mx;
  }
  if (lane < TOPK_) buf[lane] = mykeep;
  return t13;
}

// ---------- kernel 0: valid mask + zero bitmask ----------

__global__ void __launch_bounds__(BDIM) k_validmask(
    const float* __restrict__ priors,
    const float* __restrict__ gt_bboxes,
    const float* __restrict__ pad_flag,
    unsigned char* __restrict__ valid_mask,
    uint32_t* __restrict__ match_mask)
{
  int b = blockIdx.y;
  __shared__ float4 sbox[G_];
  __shared__ float  sflag[G_];
  for (int g = threadIdx.x; g < G_; g += BDIM){
    sbox[g]  = ((const float4*)gt_bboxes)[b*G_ + g];
    sflag[g] = pad_flag[b*G_ + g];
  }
  __syncthreads();
  int n = blockIdx.x*BDIM + threadIdx.x;
  if (n >= N_) return;
  float cx = priors[n*4+0], cy = priors[n*4+1];
  bool v = false;
  for (int g = 0; g < G_; ++g){
    float4 gb = sbox[g];
    bool in = (cx - gb.x > 0.0f) & (cy - gb.y > 0.0f) &
              (gb.z - cx > 0.0f) & (gb.w - cy > 0.0f) & (sflag[g] > 0.0f);
    v |= in;
  }
  size_t idx = (size_t)b*N_ + n;
  valid_mask[idx] = v ? 1 : 0;
  ((uint4*)match_mask)[idx] = make_uint4(0u,0u,0u,0u);
}

// ---------- kernel 1: per (b,g,chunk) seeded streaming top-13 ----------

__global__ void __launch_bounds__(BDIM) k_topk(
    const float* __restrict__ pred_bboxes,
    const float* __restrict__ pred_scores,
    const float* __restrict__ priors,
    const int*   __restrict__ gt_labels,
    const float* __restrict__ gt_bboxes,
    const float* __restrict__ pad_flag,
    const unsigned char* __restrict__ valid_mask,
    unsigned long long* __restrict__ ck_out,
    float* __restrict__ ci_out)
{
  #pragma clang fp contract(off)
  const int g = blockIdx.x, b = blockIdx.y, chunk = blockIdx.z;
  if (pad_flag[b*G_ + g] <= 0.0f) return;   // invalid gt: no matches

  __shared__ unsigned long long s_cbuf[4][CAPC];
  __shared__ float s_ibuf[4][CAPI];
  __shared__ unsigned long long s_fk[4][TOPK_ + 1];
  __shared__ float s_fi[4][TOPK_ + 1];

  const int tid = threadIdx.x, lane = tid & 63, wid = tid >> 6;
  unsigned long long* cbuf = s_cbuf[wid];
  float* ibuf = s_ibuf[wid];

  const float4 gb = ((const float4*)gt_bboxes)[b*G_ + g];
  const float ga  = (gb.z - gb.x) * (gb.w - gb.y);
  const float gcx = (gb.x + gb.z) * 0.5f, gcy = (gb.y + gb.w) * 0.5f;
  const int lbl = gt_labels[b*G_ + g];
  const unsigned int KEYINF = fkey(INFC);

  const float4* pb4 = (const float4*)pred_bboxes + (size_t)b*N_;
  const float4* pr4 = (const float4*)priors;
  const unsigned char* vm = valid_mask + (size_t)b*N_;
  const float* sc_b = pred_scores + (size_t)b*N_*NCLS;

  // ---- seed thresholds from a 5x5 patch around gt center per stride level ----
  // Evaluates EXACT costs/ious of 75 real anchors -> provable bounds for gates.
  auto seed_eval = [&](int t, unsigned long long& key, float& iouv){
    #pragma clang fp contract(off)
    int nk, bs; float s;
    if      (t < 25){ nk = 160; bs = 0;     s = 8.0f;  }
    else if (t < 50){ nk = 80;  bs = 25600; s = 16.0f; }
    else            { nk = 40;  bs = 32000; s = 32.0f; }
    int rem = (t < 25) ? t : ((t < 50) ? t - 25 : t - 50);
    int r = rem / 5, c = rem - 5*r;
    int ix = (int)(gcx / s) - 2, iy = (int)(gcy / s) - 2;
    ix = ix < 0 ? 0 : (ix > nk-5 ? nk-5 : ix);
    iy = iy < 0 ? 0 : (iy > nk-5 ? nk-5 : iy);
    int n = bs + (iy + r)*nk + (ix + c);
    float4 pb = pb4[n];
    float4 pr = pr4[n];
    float pa = (pb.z - pb.x) * (pb.w - pb.y);
    float lx = fmaxf(pb.x, gb.x), ly = fmaxf(pb.y, gb.y);
    float rx = fminf(pb.z, gb.z), ry = fminf(pb.w, gb.w);
    float ov = fmaxf(rx - lx, 0.0f) * fmaxf(ry - ly, 0.0f);
    float un = pa + ga - ov;
    float iou = ov / fmaxf(un, 1e-6f);
    iouv = iou;
    bool valid = vm[n] != 0;
    float invs = __uint_as_float(0x7F000000u - __float_as_uint(pr.z));
    float dx = pr.x - gcx, dy = pr.y - gcy;
    float dist = sqrtf(dx*dx + dy*dy) * invs;
    float x = valid ? sc_b[(size_t)n*NCLS + lbl] : 0.0f;
    float cst = cost_eval(iou, x, dist, valid);
    key = ((unsigned long long)fkey(cst) << 32) | (unsigned)n;
  };

  unsigned long long Tkey; bool tc48; float gthr2; float Tiou_m;
  {
    unsigned long long k0 = ~0ull, k1 = ~0ull;
    float i0 = -1.0f, i1 = -1.0f;
    if (lane < 75) seed_eval(lane, k0, i0);
    if (lane < 11) seed_eval(lane + 64, k1, i1);
    // 13th smallest key among the 75 (unique keys)
    unsigned long long T = ~0ull;
    #pragma unroll
    for (int r = 0; r < TOPK_; ++r){
      unsigned long long mn = wave_min_u64(k0 < k1 ? k0 : k1);
      if      (k0 == mn) k0 = ~0ull;
      else if (k1 == mn) k1 = ~0ull;
      T = mn;
    }
    Tkey = T + 1;                                   // keep key <= T
    float Tc = unfkey((unsigned int)(T >> 32));
    tc48 = Tc < 48.0f;                              // iou=0 => cost > 48.35
    float gt_ = 3.02f + log10f(Tc);                 // conservative margin
    gthr2 = (gt_ > 0.0f) ? gt_*gt_ : 1e30f;
    // 13th largest iou among the 75 (dups allowed)
    float ti = -1.0f;
    #pragma unroll
    for (int r = 0; r < TOPK_; ++r){
      float mx = fmaxf(i0, i1);
      #pragma unroll
      for (int m = 1; m < 64; m <<= 1) mx = fmaxf(mx, __shfl_xor(mx, m, 64));
      bool h0 = (i0 == mx), h1 = (i1 == mx);
      unsigned long long ball = __ballot(h0 | h1);
      int src = (int)(__ffsll(ball) - 1);
      if (lane == src){ if (h0) i0 = -1e30f; else i1 = -1e30f; }
      ti = mx;
    }
    Tiou_m = fmaxf(ti, 0.0f) * 0.999f;              // conservative down
  }

  int ccnt = 0, icnt = 0;

  const int nend = (chunk + 1) * NCSZ;
  for (int n = chunk*NCSZ + tid; n < nend; n += BDIM){
    float4 pb = pb4[n];
    float4 pr = pr4[n];
    float pa = (pb.z - pb.x) * (pb.w - pb.y);
    float lx = fmaxf(pb.x, gb.x), ly = fmaxf(pb.y, gb.y);
    float rx = fminf(pb.z, gb.z), ry = fminf(pb.w, gb.w);
    float ov = fmaxf(rx - lx, 0.0f) * fmaxf(ry - ly, 0.0f);
    float un = pa + ga - ov;                      // un >= max(pa,ga) > 0
    bool ipass = ov > Tiou_m * un;                // superset of {iou > Tiou}

    float invs = __uint_as_float(0x7F000000u - __float_as_uint(pr.z)); // exact 1/2^k
    float dx = pr.x - gcx, dy = pr.y - gcy;
    float dist2 = dx*dx + dy*dy;
    float d2s = dist2 * (invs * invs);
    bool valid = vm[n] != 0;
    // conservative: skip iff provably cost > Tc
    bool needcost = valid && (d2s <= gthr2) && !((ov <= 0.0f) && tc48);

    float iou = 0.0f;
    if (__any(ipass || needcost)){
      if (ipass || needcost) iou = ov / fmaxf(un, 1e-6f);
    }

    // ---- iou top-13 stream (values only; sum feeds dyn_k) ----
    {
      unsigned long long m = __ballot(ipass);
      if (m){
        int pc = __popcll(m);
        if (icnt + pc > CAPI){
          float t = compact_iou(ibuf, icnt); icnt = TOPK_;
          Tiou_m = t * 0.999f;                     // conservative down
        }
        int pos = icnt + (int)__popcll(m & ((1ull << lane) - 1ull));
        if (ipass) ibuf[pos] = iou;
        icnt += pc;
      }
    }

    // ---- cost top-13 stream ----
    unsigned long long key = ((unsigned long long)KEYINF << 32) | (unsigned)n;
    bool cpass = (!valid) && (key < Tkey);         // invalid: cost == 1e8 exactly
    if (__any(needcost)){
      if (needcost){
        float x = sc_b[(size_t)n*NCLS + lbl];
        float dist = sqrtf(dist2) * invs;          // == sqrt(d2)/stride exactly
        float c = cost_eval(iou, x, dist, true);
        key = ((unsigned long long)fkey(c) << 32) | (unsigned)n;
        cpass = key < Tkey;
      }
    }
    {
      unsigned long long m = __ballot(cpass);
      if (m){
        int pc = __popcll(m);
        if (ccnt + pc > CAPC){
          Tkey = compact_cost(cbuf, ccnt); ccnt = TOPK_;
          float Tc = unfkey((unsigned int)(Tkey >> 32));
          tc48 = Tc < 48.0f;                        // iou=0 => cost > 48.35
          float gt_ = 3.02f + log10f(Tc);           // +0.02 conservative margin
          gthr2 = (gt_ > 0.0f) ? gt_*gt_ : 1e30f;
        }
        int pos = ccnt + (int)__popcll(m & ((1ull << lane) - 1ull));
        if (cpass) cbuf[pos] = key;
        ccnt += pc;
      }
    }
  }

  // final per-wave exact selection, then cross-wave merge -> chunk result
  compact_cost(cbuf, ccnt);
  compact_iou(ibuf, icnt);
  if (lane < TOPK_){ s_fk[wid][lane] = cbuf[lane]; s_fi[wid][lane] = ibuf[lane]; }
  if (lane == TOPK_){ s_fk[wid][TOPK_] = ~0ull; s_fi[wid][TOPK_] = -1e30f; }
  __syncthreads();

  if (tid == 0){
    size_t base = (((size_t)b*G_ + g)*NCHUNK + chunk)*TOPK_;
    // merge 4 descending iou lists -> 13 descending
    {
      int p0 = 0, p1 = 0, p2 = 0, p3 = 0;
      for (int r = 0; r < TOPK_; ++r){
        float v0 = s_fi[0][p0], v1 = s_fi[1][p1], v2 = s_fi[2][p2], v3 = s_fi[3][p3];
        float mx = fmaxf(fmaxf(v0, v1), fmaxf(v2, v3));
        if      (v0 == mx) p0++;
        else if (v1 == mx) p1++;
        else if (v2 == mx) p2++;
        else               p3++;
        ci_out[base + r] = mx;
      }
    }
    // merge 4 ascending key lists -> 13 ascending
    {
      int q0 = 0, q1 = 0, q2 = 0, q3 = 0;
      for (int r = 0; r < TOPK_; ++r){
        unsigned long long k0 = s_fk[0][q0], k1 = s_fk[1][q1];
        unsigned long long k2 = s_fk[2][q2], k3 = s_fk[3][q3];
        unsigned long long mn = k0 < k1 ? k0 : k1;
        unsigned long long mn2 = k2 < k3 ? k2 : k3;
        mn = mn < mn2 ? mn : mn2;
        if      (k0 == mn) q0++;
        else if (k1 == mn) q1++;
        else if (k2 == mn) q2++;
        else               q3++;
        ck_out[base + r] = mn;
      }
    }
  }
}

// ---------- kernel 1b: merge NCHUNK chunk results, compute dyn_k, scatter ----------

__global__ void __launch_bounds__(64) k_merge(
    const float* __restrict__ pad_flag,
    const unsigned long long* __restrict__ ck,
    const float* __restrict__ ci,
    uint32_t* __restrict__ match_mask)
{
  const int g = blockIdx.x, b = blockIdx.y;
  if (threadIdx.x != 0) return;
  if (pad_flag[b*G_ + g] <= 0.0f) return;

  const size_t base = ((size_t)b*G_ + g)*NCHUNK*TOPK_;
  const unsigned long long* K = ck + base;
  const float* I = ci + base;

  // merge 4 descending iou lists; sum top-13 in descending order
  int p0 = 0, p1 = 0, p2 = 0, p3 = 0; float s = 0.0f;
  for (int r = 0; r < TOPK_; ++r){
    float v0 = (p0 < TOPK_) ? I[0*TOPK_ + p0] : -1e30f;
    float v1 = (p1 < TOPK_) ? I[1*TOPK_ + p1] : -1e30f;
    float v2 = (p2 < TOPK_) ? I[2*TOPK_ + p2] : -1e30f;
    float v3 = (p3 < TOPK_) ? I[3*TOPK_ + p3] : -1e30f;
    float mx = fmaxf(fmaxf(v0, v1), fmaxf(v2, v3));
    if      (v0 == mx) p0++;
    else if (v1 == mx) p1++;
    else if (v2 == mx) p2++;
    else               p3++;
    s += fmaxf(mx, 0.0f);                        // sentinels add 0
  }
  int dynk = (int)s;                             // trunc toward zero
  if (dynk < 1) dynk = 1;
  if (dynk > TOPK_) dynk = TOPK_;

  // merge 4 ascending key lists; scatter first dynk
  int q0 = 0, q1 = 0, q2 = 0, q3 = 0;
  for (int r = 0; r < dynk; ++r){
    unsigned long long k0 = (q0 < TOPK_) ? K[0*TOPK_ + q0] : ~0ull;
    unsigned long long k1 = (q1 < TOPK_) ? K[1*TOPK_ + q1] : ~0ull;
    unsigned long long k2 = (q2 < TOPK_) ? K[2*TOPK_ + q2] : ~0ull;
    unsigned long long k3 = (q3 < TOPK_) ? K[3*TOPK_ + q3] : ~0ull;
    unsigned long long mn = k0 < k1 ? k0 : k1;
    unsigned long long mn2 = k2 < k3 ? k2 : k3;
    mn = mn < mn2 ? mn : mn2;
    if      (k0 == mn) q0++;
    else if (k1 == mn) q1++;
    else if (k2 == mn) q2++;
    else               q3++;
    int n = (int)(mn & 0xffffffffu);
    if (n < N_)                                  // insurance vs sentinel pick
      atomicOr(&match_mask[((size_t)b*N_ + n)*4 + (g >> 5)], 1u << (g & 31));
  }
}

// ---------- kernel 2: per (b,n) final assignment ----------
// fast path count<=1; count>1 resolved wave-cooperatively (g across lanes)

__global__ void __launch_bounds__(BDIM) k_assign(
    const float* __restrict__ pred_bboxes,
    const float* __restrict__ pred_scores,
    const float* __restrict__ priors,
    const int*   __restrict__ gt_labels,
    const float* __restrict__ gt_bboxes,
    const unsigned char* __restrict__ valid_mask,
    const uint32_t* __restrict__ match_mask,
    float* __restrict__ out)
{
  #pragma clang fp contract(off)
  const int b = blockIdx.y;
  __shared__ float4 sbox[G_];
  __shared__ int    slbl[G_];
  __shared__ float  sga[G_], sgcx[G_], sgcy[G_];
  for (int g = threadIdx.x; g < G_; g += BDIM){
    float4 q = ((const float4*)gt_bboxes)[b*G_ + g];
    sbox[g] = q; slbl[g] = gt_labels[b*G_ + g];
    sga[g]  = (q.z - q.x) * (q.w - q.y);
    sgcx[g] = (q.x + q.z) * 0.5f;
    sgcy[g] = (q.y + q.w) * 0.5f;
  }
  __syncthreads();
  int n = blockIdx.x*BDIM + threadIdx.x;
  if (n >= N_) return;                 // N_ is a multiple of 64: wave-aligned exit
  const int lane = threadIdx.x & 63;
  size_t idx = (size_t)b*N_ + n;
  uint4 mm = ((const uint4*)match_mask)[idx];
  int count = __popc(mm.x) + __popc(mm.y) + __popc(mm.z) + __popc(mm.w);

  float lblv = (float)NCLS;
  float4 ob = make_float4(0.f, 0.f, 0.f, 0.f);
  float met = 0.0f;

  if (__any(count > 0)){
    float4 pb = make_float4(0.f,0.f,0.f,0.f); float pa = 0.0f;
    if (count > 0){
      pb = ((const float4*)pred_bboxes)[idx];
      pa = (pb.z - pb.x) * (pb.w - pb.y);
    }
    if (count == 1){
      int mg = mm.x ? (__ffs(mm.x) - 1) :
               mm.y ? (31 + __ffs(mm.y)) :
               mm.z ? (63 + __ffs(mm.z)) : (95 + __ffs(mm.w));
      float4 q = sbox[mg];
      float lx = fmaxf(pb.x, q.x), ly = fmaxf(pb.y, q.y);
      float rx = fminf(pb.z, q.z), ry = fminf(pb.w, q.w);
      float ov = fmaxf(rx - lx, 0.0f) * fmaxf(ry - ly, 0.0f);
      float iou = ov / fmaxf(pa + sga[mg] - ov, 1e-6f);
      lblv = (float)slbl[mg]; ob = q; met = iou;
    }
    unsigned long long heavy = __ballot(count > 1);
    if (heavy){
      float4 pr = make_float4(0.f,0.f,0.f,0.f); int hv0 = 0;
      if (count > 1){
        pr = ((const float4*)priors)[n];
        hv0 = valid_mask[idx];
      }
      while (heavy){
        int src = (int)(__ffsll((unsigned long long)heavy) - 1);
        heavy &= heavy - 1ull;
        // broadcast the heavy anchor
        float hx1 = __shfl(pb.x, src, 64), hy1 = __shfl(pb.y, src, 64);
        float hx2 = __shfl(pb.z, src, 64), hy2 = __shfl(pb.w, src, 64);
        float hpa = __shfl(pa,   src, 64);
        float hcx = __shfl(pr.x, src, 64), hcy = __shfl(pr.y, src, 64);
        float hst = __shfl(pr.z, src, 64);
        int   hv  = __shfl(hv0,  src, 64);
        int   hn  = __shfl(n,    src, 64);
        float hinvs = __uint_as_float(0x7F000000u - __float_as_uint(hst));
        const float* hrow = pred_scores + ((size_t)b*N_ + hn)*(size_t)NCLS;

        unsigned long long bk = ~0ull;
        #pragma unroll
        for (int h = 0; h < 2; ++h){
          int g = lane + h*64;
          if (g < G_){
            float4 q = sbox[g];
            float lx = fmaxf(hx1, q.x), ly = fmaxf(hy1, q.y);
            float rx = fminf(hx2, q.z), ry = fminf(hy2, q.w);
            float ov = fmaxf(rx - lx, 0.0f) * fmaxf(ry - ly, 0.0f);
            float un = hpa + sga[g] - ov;
            float iou = ov / fmaxf(un, 1e-6f);
            float dx = hcx - sgcx[g], dy = hcy - sgcy[g];
            float dist = sqrtf(dx*dx + dy*dy) * hinvs;
            float x = hrow[slbl[g]];
            float c = cost_eval(iou, x, dist, hv != 0);
            unsigned long long key = ((unsigned long long)fkey(c) << 32) | (unsigned)g;
            bk = key < bk ? key : bk;
          }
        }
        // 64-lane min reduce (cost ties -> smaller g, matches jnp.argmin)
        bk = wave_min_u64(bk);
        if (lane == src){
          int gw = (int)(bk & 0xffffffffu);
          float4 q = sbox[gw];
          float lx = fmaxf(pb.x, q.x), ly = fmaxf(pb.y, q.y);
          float rx = fminf(pb.z, q.z), ry = fminf(pb.w, q.w);
          float ov = fmaxf(rx - lx, 0.0f) * fmaxf(ry - ly, 0.0f);
          met  = ov / fmaxf(pa + sga[gw] - ov, 1e-6f);
          lblv = (float)slbl[gw];
          ob = q;
        }
      }
    }
  }

  out[idx] = lblv;                                   // assigned_labels
  out[(size_t)B_*N_ + idx] = 1.0f;                   // weights
  ((float4*)(out + (size_t)2*B_*N_))[idx] = ob;      // assigned_bboxes
  out[(size_t)6*B_*N_ + idx] = met;                  // assign_metrics
}

// ---------- launch ----------

extern "C" void kernel_launch(void* const* d_in, const int* in_sizes, int n_in,
                              void* d_out, int out_size, void* d_ws, size_t ws_size,
                              hipStream_t stream) {
  const float* pred_bboxes = (const float*)d_in[0];
  const float* pred_scores = (const float*)d_in[1];
  const float* priors      = (const float*)d_in[2];
  const int*   gt_labels   = (const int*)  d_in[3];
  const float* gt_bboxes   = (const float*)d_in[4];
  const float* pad_flag    = (const float*)d_in[5];
  float* out = (float*)d_out;

  // ws layout: match bitmask | valid mask | chunk keys | chunk ious
  const size_t MASK_B  = (size_t)B_*N_*4*sizeof(uint32_t);               // 4,300,800
  const size_t VALID_B = ((size_t)B_*N_ + 255) & ~(size_t)255;           //   268,800
  const size_t CK_B    = (size_t)B_*G_*NCHUNK*TOPK_*sizeof(unsigned long long); // 332,800
  uint32_t* match_mask = (uint32_t*)d_ws;
  unsigned char* valid_mask = (unsigned char*)d_ws + MASK_B;
  unsigned long long* ck = (unsigned long long*)((char*)d_ws + MASK_B + VALID_B);
  float* ci = (float*)((char*)d_ws + MASK_B + VALID_B + CK_B);

  dim3 gridN((N_ + BDIM - 1)/BDIM, B_);
  dim3 gridG(G_, B_, NCHUNK);
  dim3 gridM(G_, B_);

  k_validmask<<<gridN, BDIM, 0, stream>>>(priors, gt_bboxes, pad_flag,
                                          valid_mask, match_mask);
  k_topk<<<gridG, BDIM, 0, stream>>>(pred_bboxes, pred_scores, priors, gt_labels,
                                     gt_bboxes, pad_flag, valid_mask, ck, ci);
  k_merge<<<gridM, 64, 0, stream>>>(pad_flag, ck, ci, match_mask);
  k_assign<<<gridN, BDIM, 0, stream>>>(pred_bboxes, pred_scores, priors, gt_labels,
                                       gt_bboxes, valid_mask, match_mask, out);
}

// Round 7
// 76.665 us; speedup vs baseline: 8.7043x; 1.7135x over previous
//
#include <hip/hip_runtime.h>
#include <stdint.h>

#define BDIM 256
#define B_   8
#define NCLS 80
#define G_   100
#define N_   33600
#define TOPK_ 13
#define NCHUNK 2
#define TILES 525          // 400 (level0 20x20) + 100 (level1 10x10) + 25 (level2 5x5), 8x8 anchors each
#define CAPC 160           // per-wave cost candidate buffer (u64 keys)
#define CAPI 160           // per-wave iou candidate buffer (f32)
#define INFC 1e8f

// ---------- helpers ----------

__device__ __forceinline__ unsigned int fkey(float f){
  unsigned int u = __float_as_uint(f);
  return (u & 0x80000000u) ? ~u : (u | 0x80000000u);  // monotonic float->uint
}
__device__ __forceinline__ float unfkey(unsigned int k){
  unsigned int u = (k & 0x80000000u) ? (k & 0x7fffffffu) : ~k;
  return __uint_as_float(u);
}

// cost = bce*(scale^2) + (-log(iou+eps)*3) + 10^(dist-3); INF-masked by valid
__device__ __forceinline__ float cost_eval(float iou, float x, float dist, bool valid){
  #pragma clang fp contract(off)
  float prior = exp2f((dist - 3.0f) * 3.321928094887362f);   // 10^(dist-3)
  float iouc  = -logf(iou + 1e-7f) * 3.0f;
  float sig   = 1.0f / (1.0f + expf(-x));
  float sc    = iou - sig;
  float bce   = fmaxf(x, 0.0f) + log1pf(expf(-fabsf(x))) - x * iou;
  float c     = bce * (sc * sc) + iouc + prior;
  return valid ? c : INFC;
}

__device__ __forceinline__ unsigned long long wave_min_u64(unsigned long long v){
  #pragma unroll
  for (int m = 1; m < 64; m <<= 1){
    unsigned int lo = (unsigned int)__shfl_xor((int)(unsigned int)v, m, 64);
    unsigned int hi = (unsigned int)__shfl_xor((int)(unsigned int)(v >> 32), m, 64);
    unsigned long long o = ((unsigned long long)hi << 32) | lo;
    v = o < v ? o : v;
  }
  return v;
}

// tile id -> level geometry. Tiles are 8x8 spatial patches; levels: 160x160(s=8), 80x80(s=16), 40x40(s=32).
__device__ __forceinline__ void tile_params(int t, int& W, int& base, int& trow, int& tcol,
                                            float& s, float& invs){
  if (t < 400){            W = 160; base = 0;     s = 8.0f;  invs = 0.125f;
    trow = (t/20)*8;  tcol = (t - (t/20)*20)*8; }
  else if (t < 500){ int u = t - 400; W = 80; base = 25600; s = 16.0f; invs = 0.0625f;
    trow = (u/10)*8; tcol = (u - (u/10)*10)*8; }
  else {             int u = t - 500; W = 40; base = 32000; s = 32.0f; invs = 0.03125f;
    trow = (u/5)*8;  tcol = (u - (u/5)*5)*8; }
}

// exact selection of 13 smallest u64 keys from buf[0..cnt) (cnt<=CAPC). keys unique.
__device__ unsigned long long compact_cost(unsigned long long* buf, int cnt){
  const int lane = threadIdx.x & 63;
  unsigned long long a0 = (lane       < cnt) ? buf[lane]       : ~0ull;
  unsigned long long a1 = (lane + 64  < cnt) ? buf[lane + 64]  : ~0ull;
  unsigned long long a2 = (lane + 128 < cnt) ? buf[lane + 128] : ~0ull;
  unsigned long long mykeep = ~0ull, t13 = ~0ull;
  #pragma unroll
  for (int r = 0; r < TOPK_; ++r){
    unsigned long long v = a0 < a1 ? a0 : a1; v = v < a2 ? v : a2;
    unsigned long long mn = wave_min_u64(v);
    if      (a0 == mn) a0 = ~0ull;
    else if (a1 == mn) a1 = ~0ull;
    else if (a2 == mn) a2 = ~0ull;
    if (lane == r) mykeep = mn;
    t13 = mn;
  }
  if (lane < TOPK_) buf[lane] = mykeep;
  return t13;
}

// exact selection of 13 largest floats (dups allowed) from buf[0..cnt).
__device__ float compact_iou(float* buf, int cnt){
  const int lane = threadIdx.x & 63;
  float a0 = (lane       < cnt) ? buf[lane]       : -1.0f;
  float a1 = (lane + 64  < cnt) ? buf[lane + 64]  : -1.0f;
  float a2 = (lane + 128 < cnt) ? buf[lane + 128] : -1.0f;
  float mykeep = -1.0f, t13 = -1.0f;
  #pragma unroll
  for (int r = 0; r < TOPK_; ++r){
    float mx = fmaxf(fmaxf(a0, a1), a2);
    #pragma unroll
    for (int m = 1; m < 64; m <<= 1) mx = fmaxf(mx, __shfl_xor(mx, m, 64));
    bool h0 = (a0 == mx), h1 = (a1 == mx), h2 = (a2 == mx);
    unsigned long long ball = __ballot(h0 | h1 | h2);
    int src = (int)(__ffsll(ball) - 1);
    if (lane == src){
      if (h0) a0 = -1.0f; else if (h1) a1 = -1.0f; else a2 = -1.0f;
    }
    if (lane == r) mykeep = mx;
    t13 = mx;
  }
  if (lane < TOPK_) buf[lane] = mykeep;
  return t13;
}

// ---------- kernel 0: valid mask + zero bitmask ----------

__global__ void __launch_bounds__(BDIM) k_validmask(
    const float* __restrict__ priors,
    const float* __restrict__ gt_bboxes,
    const float* __restrict__ pad_flag,
    unsigned char* __restrict__ valid_mask,
    uint32_t* __restrict__ match_mask)
{
  int b = blockIdx.y;
  __shared__ float4 sbox[G_];
  __shared__ float  sflag[G_];
  for (int g = threadIdx.x; g < G_; g += BDIM){
    sbox[g]  = ((const float4*)gt_bboxes)[b*G_ + g];
    sflag[g] = pad_flag[b*G_ + g];
  }
  __syncthreads();
  int n = blockIdx.x*BDIM + threadIdx.x;
  if (n >= N_) return;
  float cx = priors[n*4+0], cy = priors[n*4+1];
  bool v = false;
  for (int g = 0; g < G_; ++g){
    float4 gb = sbox[g];
    bool in = (cx - gb.x > 0.0f) & (cy - gb.y > 0.0f) &
              (gb.z - cx > 0.0f) & (gb.w - cy > 0.0f) & (sflag[g] > 0.0f);
    v |= in;
  }
  size_t idx = (size_t)b*N_ + n;
  valid_mask[idx] = v ? 1 : 0;
  ((uint4*)match_mask)[idx] = make_uint4(0u,0u,0u,0u);
}

// ---------- kernel 0b: per-tile aggregates (union pred bbox + any-valid) ----------

__global__ void __launch_bounds__(64) k_tileprep(
    const float* __restrict__ pred_bboxes,
    const unsigned char* __restrict__ valid_mask,
    float4* __restrict__ tile_agg,
    uint32_t* __restrict__ tile_flag)
{
  int t = blockIdx.x, b = blockIdx.y, l = threadIdx.x;
  int W, base, trow, tcol; float s, invs;
  tile_params(t, W, base, trow, tcol, s, invs);
  int n = base + (trow + (l >> 3))*W + tcol + (l & 7);
  size_t idx = (size_t)b*N_ + n;
  float4 pb = ((const float4*)pred_bboxes)[idx];
  int v = valid_mask[idx];
  float x1 = pb.x, y1 = pb.y, x2 = pb.z, y2 = pb.w;
  #pragma unroll
  for (int m = 1; m < 64; m <<= 1){
    x1 = fminf(x1, __shfl_xor(x1, m, 64));
    y1 = fminf(y1, __shfl_xor(y1, m, 64));
    x2 = fmaxf(x2, __shfl_xor(x2, m, 64));
    y2 = fmaxf(y2, __shfl_xor(y2, m, 64));
  }
  unsigned long long anyb = __ballot(v != 0);
  if (l == 0){
    tile_agg [(size_t)b*TILES + t] = make_float4(x1, y1, x2, y2);
    tile_flag[(size_t)b*TILES + t] = (anyb != 0ull) ? 1u : 0u;
  }
}

// ---------- kernel 1: per (b,g,chunk) tile-pruned streaming top-13 ----------

__global__ void __launch_bounds__(BDIM) k_topk(
    const float* __restrict__ pred_bboxes,
    const float* __restrict__ pred_scores,
    const int*   __restrict__ gt_labels,
    const float* __restrict__ gt_bboxes,
    const float* __restrict__ pad_flag,
    const unsigned char* __restrict__ valid_mask,
    const float4* __restrict__ tile_agg,
    const uint32_t* __restrict__ tile_flag,
    unsigned long long* __restrict__ ck_out,
    float* __restrict__ ci_out)
{
  #pragma clang fp contract(off)
  const int g = blockIdx.x, b = blockIdx.y, chunk = blockIdx.z;
  if (pad_flag[b*G_ + g] <= 0.0f) return;   // invalid gt: no matches

  __shared__ unsigned long long s_cbuf[4][CAPC];
  __shared__ float s_ibuf[4][CAPI];
  __shared__ unsigned long long s_fk[4][TOPK_ + 1];
  __shared__ float s_fi[4][TOPK_ + 1];

  const int tid = threadIdx.x, lane = tid & 63, wid = tid >> 6;
  unsigned long long* cbuf = s_cbuf[wid];
  float* ibuf = s_ibuf[wid];

  const float4 gb = ((const float4*)gt_bboxes)[b*G_ + g];
  const float ga  = (gb.z - gb.x) * (gb.w - gb.y);
  const float gcx = (gb.x + gb.z) * 0.5f, gcy = (gb.y + gb.w) * 0.5f;
  const int lbl = gt_labels[b*G_ + g];
  const unsigned int KEYINF = fkey(INFC);

  const float4* pb4 = (const float4*)pred_bboxes + (size_t)b*N_;
  const unsigned char* vm = valid_mask + (size_t)b*N_;
  const float* sc_b = pred_scores + (size_t)b*N_*NCLS;
  const float4* tag = tile_agg + (size_t)b*TILES;
  const uint32_t* tfl = tile_flag + (size_t)b*TILES;

  // ---- seed: EXACT costs/ious of 75 real anchors (5x5 patch per level) ----
  auto seed_eval = [&](int t, float& cst, float& iouv){
    #pragma clang fp contract(off)
    int nk, bs; float s, invs;
    if      (t < 25){ nk = 160; bs = 0;     s = 8.0f;  invs = 0.125f;   }
    else if (t < 50){ nk = 80;  bs = 25600; s = 16.0f; invs = 0.0625f;  }
    else            { nk = 40;  bs = 32000; s = 32.0f; invs = 0.03125f; }
    int rem = (t < 25) ? t : ((t < 50) ? t - 25 : t - 50);
    int r = rem / 5, c = rem - 5*r;
    int ix = (int)(gcx / s) - 2, iy = (int)(gcy / s) - 2;
    ix = ix < 0 ? 0 : (ix > nk-5 ? nk-5 : ix);
    iy = iy < 0 ? 0 : (iy > nk-5 ? nk-5 : iy);
    int col = ix + c, row = iy + r;
    int n = bs + row*nk + col;
    float4 pb = pb4[n];
    float pa = (pb.z - pb.x) * (pb.w - pb.y);
    float lx = fmaxf(pb.x, gb.x), ly = fmaxf(pb.y, gb.y);
    float rx = fminf(pb.z, gb.z), ry = fminf(pb.w, gb.w);
    float ov = fmaxf(rx - lx, 0.0f) * fmaxf(ry - ly, 0.0f);
    float un = pa + ga - ov;
    float iou = ov / fmaxf(un, 1e-6f);
    iouv = iou;
    bool valid = vm[n] != 0;
    float px = ((float)col + 0.5f)*s, py = ((float)row + 0.5f)*s;   // == priors (exact)
    float dx = px - gcx, dy = py - gcy;
    float dist = sqrtf(dx*dx + dy*dy) * invs;
    float x = valid ? sc_b[(size_t)n*NCLS + lbl] : 0.0f;
    cst = cost_eval(iou, x, dist, valid);
  };

  float c0 = 3e38f, c1 = 3e38f, i0 = -1.0f, i1 = -1.0f;
  seed_eval(lane, c0, i0);
  if (lane < 11) seed_eval(lane + 64, c1, i1);

  // probe thresholds: smallest cost level / largest iou level with >=13 seeds qualifying.
  float T = INFC;
  {
    const float lvs[7] = {47.0f, 24.0f, 12.0f, 6.0f, 3.0f, 1.5f, 0.75f};
    #pragma unroll
    for (int i = 0; i < 7; ++i){
      int cnt = __popcll(__ballot(c0 <= lvs[i])) + __popcll(__ballot(c1 <= lvs[i]));
      if (cnt >= TOPK_) T = lvs[i];
    }
  }
  float Tiou_m = 0.0f;
  {
    const float ivs[8] = {0.02f, 0.05f, 0.1f, 0.15f, 0.22f, 0.3f, 0.4f, 0.5f};
    #pragma unroll
    for (int i = 0; i < 8; ++i){
      int cnt = __popcll(__ballot(i0 >= ivs[i])) + __popcll(__ballot(i1 >= ivs[i]));
      if (cnt >= TOPK_) Tiou_m = ivs[i] * 0.999f;
    }
  }
  unsigned long long Tkey = ((unsigned long long)fkey(T) << 32) | 0xFFFFFFFFull;
  bool  tc48  = T < 48.0f;
  float gt_   = 3.02f + log10f(T);
  float gthr2 = gt_ * gt_;                // T >= 0.75 -> positive

  int ccnt = 0, icnt = 0;

  // ---- rare: bound is 1e8 -> invalid anchors (cost exactly 1e8, index tie-break) may rank.
  // Sweep lowest-index invalid anchors once (chunk 0, wave 0 only).
  int sweep_nend = 0;
  if (chunk == 0 && wid == 0 && T == INFC){
    int found = 0, base = 0;
    while (found < TOPK_ && base < N_){
      int n = base + lane;
      bool inv = (vm[n] == 0);
      unsigned long long m = __ballot(inv);
      int pc = __popcll(m);
      int pos = ccnt + (int)__popcll(m & ((1ull << lane) - 1ull));
      if (inv) cbuf[pos] = ((unsigned long long)KEYINF << 32) | (unsigned)n;
      ccnt += pc;                          // bounded: <=76 before first 13 found
      found += pc;
      base += 64;
    }
    sweep_nend = base;                     // suppress in-loop dup for n < sweep_nend
  }

  // ---- tile loop: this wave's tile subrange of this chunk ----
  const int lo_c = (chunk == 0) ? 0 : 263;
  const int hi_c = (chunk == 0) ? 263 : TILES;
  const int per  = (hi_c - lo_c + 3) >> 2;
  const int lo_w = lo_c + wid*per;
  const int hi_w = min(hi_c, lo_w + per);

  for (int tb = lo_w; tb < hi_w; tb += 64){
    int tt2 = tb + lane;
    bool pass = false;
    if (tt2 < hi_w){
      float4 ag = tag[tt2];
      uint32_t fl2 = tfl[tt2];
      int W, bse, trow, tcol; float s, invs;
      tile_params(tt2, W, bse, trow, tcol, s, invs);
      bool inter = (fminf(ag.z, gb.z) > fmaxf(ag.x, gb.x)) &&
                   (fminf(ag.w, gb.w) > fmaxf(ag.y, gb.y));       // some anchor may have ov>0
      float rx0 = ((float)tcol + 0.5f)*s, rx1 = ((float)tcol + 7.5f)*s;
      float ry0 = ((float)trow + 0.5f)*s, ry1 = ((float)trow + 7.5f)*s;
      float ddx = fmaxf(0.0f, fmaxf(rx0 - gcx, gcx - rx1));        // <= per-anchor |dx| (FP-monotone)
      float ddy = fmaxf(0.0f, fmaxf(ry0 - gcy, gcy - ry1));
      float md2s = (ddx*ddx + ddy*ddy) * (invs*invs);
      bool costok = (fl2 != 0) && (md2s <= gthr2) && (inter || !tc48);
      pass = inter || costok;
    }
    unsigned long long pm = __ballot(pass);
    while (pm){
      int bit = (int)(__ffsll(pm) - 1);
      pm &= pm - 1ull;
      const int tt = tb + bit;                      // wave-uniform tile

      int W, bse, trow, tcol; float s, invs;
      tile_params(tt, W, bse, trow, tcol, s, invs);
      int row = trow + (lane >> 3), col = tcol + (lane & 7);
      int n = bse + row*W + col;
      float px = ((float)col + 0.5f)*s, py = ((float)row + 0.5f)*s;   // == priors (exact)
      float4 pb = pb4[n];
      float pa = (pb.z - pb.x) * (pb.w - pb.y);
      float lx = fmaxf(pb.x, gb.x), ly = fmaxf(pb.y, gb.y);
      float rx = fminf(pb.z, gb.z), ry = fminf(pb.w, gb.w);
      float ov = fmaxf(rx - lx, 0.0f) * fmaxf(ry - ly, 0.0f);
      float un = pa + ga - ov;
      bool ipass = ov > Tiou_m * un;

      float dx = px - gcx, dy = py - gcy;
      float dist2 = dx*dx + dy*dy;
      float d2s = dist2 * (invs * invs);
      bool valid = vm[n] != 0;
      bool needcost = valid && (d2s <= gthr2) && !((ov <= 0.0f) && tc48);

      float iou = 0.0f;
      if (__any(ipass || needcost)){
        if (ipass || needcost) iou = ov / fmaxf(un, 1e-6f);
      }

      // ---- iou top-13 stream ----
      {
        unsigned long long m = __ballot(ipass);
        if (m){
          int pc = __popcll(m);
          if (icnt + pc > CAPI){
            float t = compact_iou(ibuf, icnt); icnt = TOPK_;
            Tiou_m = t * 0.999f;
          }
          int pos = icnt + (int)__popcll(m & ((1ull << lane) - 1ull));
          if (ipass) ibuf[pos] = iou;
          icnt += pc;
        }
      }

      // ---- cost top-13 stream ----
      unsigned long long key = ((unsigned long long)KEYINF << 32) | (unsigned)n;
      bool cpass = (!valid) && (key < Tkey) && (n >= sweep_nend);
      if (__any(needcost)){
        if (needcost){
          float x = sc_b[(size_t)n*NCLS + lbl];
          float dist = sqrtf(dist2) * invs;
          float c = cost_eval(iou, x, dist, true);
          key = ((unsigned long long)fkey(c) << 32) | (unsigned)n;
          cpass = key < Tkey;
        }
      }
      {
        unsigned long long m = __ballot(cpass);
        if (m){
          int pc = __popcll(m);
          if (ccnt + pc > CAPC){
            Tkey = compact_cost(cbuf, ccnt); ccnt = TOPK_;
            float Tc = unfkey((unsigned int)(Tkey >> 32));
            tc48 = Tc < 48.0f;
            float gq = 3.02f + log10f(Tc);
            gthr2 = (gq > 0.0f) ? gq*gq : 1e30f;
          }
          int pos = ccnt + (int)__popcll(m & ((1ull << lane) - 1ull));
          if (cpass) cbuf[pos] = key;
          ccnt += pc;
        }
      }
    }
  }

  // final per-wave exact selection, then cross-wave merge -> chunk result
  compact_cost(cbuf, ccnt);
  compact_iou(ibuf, icnt);
  if (lane < TOPK_){ s_fk[wid][lane] = cbuf[lane]; s_fi[wid][lane] = ibuf[lane]; }
  if (lane == TOPK_){ s_fk[wid][TOPK_] = ~0ull; s_fi[wid][TOPK_] = -1e30f; }
  __syncthreads();

  if (tid == 0){
    size_t base = (((size_t)b*G_ + g)*NCHUNK + chunk)*TOPK_;
    {
      int p0 = 0, p1 = 0, p2 = 0, p3 = 0;
      for (int r = 0; r < TOPK_; ++r){
        float v0 = s_fi[0][p0], v1 = s_fi[1][p1], v2 = s_fi[2][p2], v3 = s_fi[3][p3];
        float mx = fmaxf(fmaxf(v0, v1), fmaxf(v2, v3));
        if      (v0 == mx) p0++;
        else if (v1 == mx) p1++;
        else if (v2 == mx) p2++;
        else               p3++;
        ci_out[base + r] = mx;
      }
    }
    {
      int q0 = 0, q1 = 0, q2 = 0, q3 = 0;
      for (int r = 0; r < TOPK_; ++r){
        unsigned long long k0 = s_fk[0][q0], k1 = s_fk[1][q1];
        unsigned long long k2 = s_fk[2][q2], k3 = s_fk[3][q3];
        unsigned long long mn = k0 < k1 ? k0 : k1;
        unsigned long long mn2 = k2 < k3 ? k2 : k3;
        mn = mn < mn2 ? mn : mn2;
        if      (k0 == mn) q0++;
        else if (k1 == mn) q1++;
        else if (k2 == mn) q2++;
        else               q3++;
        ck_out[base + r] = mn;
      }
    }
  }
}

// ---------- kernel 1b: merge NCHUNK chunk results, compute dyn_k, scatter ----------

__global__ void __launch_bounds__(64) k_merge(
    const float* __restrict__ pad_flag,
    const unsigned long long* __restrict__ ck,
    const float* __restrict__ ci,
    uint32_t* __restrict__ match_mask)
{
  const int g = blockIdx.x, b = blockIdx.y;
  if (threadIdx.x != 0) return;
  if (pad_flag[b*G_ + g] <= 0.0f) return;

  const size_t base = ((size_t)b*G_ + g)*NCHUNK*TOPK_;
  const unsigned long long* K = ck + base;
  const float* I = ci + base;

  int p0 = 0, p1 = 0; float s = 0.0f;
  for (int r = 0; r < TOPK_; ++r){
    float v0 = (p0 < TOPK_) ? I[p0]          : -1e30f;
    float v1 = (p1 < TOPK_) ? I[TOPK_ + p1]  : -1e30f;
    float mx = fmaxf(v0, v1);
    if (v0 == mx) p0++; else p1++;
    s += fmaxf(mx, 0.0f);
  }
  int dynk = (int)s;
  if (dynk < 1) dynk = 1;
  if (dynk > TOPK_) dynk = TOPK_;

  int q0 = 0, q1 = 0;
  for (int r = 0; r < dynk; ++r){
    unsigned long long k0 = (q0 < TOPK_) ? K[q0]         : ~0ull;
    unsigned long long k1 = (q1 < TOPK_) ? K[TOPK_ + q1] : ~0ull;
    unsigned long long mn = k0 < k1 ? k0 : k1;
    if (k0 == mn) q0++; else q1++;
    int n = (int)(mn & 0xffffffffu);
    if (n < N_)
      atomicOr(&match_mask[((size_t)b*N_ + n)*4 + (g >> 5)], 1u << (g & 31));
  }
}

// ---------- kernel 2: per (b,n) final assignment ----------
// fast path count<=1; count>1 resolved wave-cooperatively (g across lanes)

__global__ void __launch_bounds__(BDIM) k_assign(
    const float* __restrict__ pred_bboxes,
    const float* __restrict__ pred_scores,
    const float* __restrict__ priors,
    const int*   __restrict__ gt_labels,
    const float* __restrict__ gt_bboxes,
    const unsigned char* __restrict__ valid_mask,
    const uint32_t* __restrict__ match_mask,
    float* __restrict__ out)
{
  #pragma clang fp contract(off)
  const int b = blockIdx.y;
  __shared__ float4 sbox[G_];
  __shared__ int    slbl[G_];
  __shared__ float  sga[G_], sgcx[G_], sgcy[G_];
  for (int g = threadIdx.x; g < G_; g += BDIM){
    float4 q = ((const float4*)gt_bboxes)[b*G_ + g];
    sbox[g] = q; slbl[g] = gt_labels[b*G_ + g];
    sga[g]  = (q.z - q.x) * (q.w - q.y);
    sgcx[g] = (q.x + q.z) * 0.5f;
    sgcy[g] = (q.y + q.w) * 0.5f;
  }
  __syncthreads();
  int n = blockIdx.x*BDIM + threadIdx.x;
  if (n >= N_) return;
  const int lane = threadIdx.x & 63;
  size_t idx = (size_t)b*N_ + n;
  uint4 mm = ((const uint4*)match_mask)[idx];
  int count = __popc(mm.x) + __popc(mm.y) + __popc(mm.z) + __popc(mm.w);

  float lblv = (float)NCLS;
  float4 ob = make_float4(0.f, 0.f, 0.f, 0.f);
  float met = 0.0f;

  if (__any(count > 0)){
    float4 pb = make_float4(0.f,0.f,0.f,0.f); float pa = 0.0f;
    if (count > 0){
      pb = ((const float4*)pred_bboxes)[idx];
      pa = (pb.z - pb.x) * (pb.w - pb.y);
    }
    if (count == 1){
      int mg = mm.x ? (__ffs(mm.x) - 1) :
               mm.y ? (31 + __ffs(mm.y)) :
               mm.z ? (63 + __ffs(mm.z)) : (95 + __ffs(mm.w));
      float4 q = sbox[mg];
      float lx = fmaxf(pb.x, q.x), ly = fmaxf(pb.y, q.y);
      float rx = fminf(pb.z, q.z), ry = fminf(pb.w, q.w);
      float ov = fmaxf(rx - lx, 0.0f) * fmaxf(ry - ly, 0.0f);
      float iou = ov / fmaxf(pa + sga[mg] - ov, 1e-6f);
      lblv = (float)slbl[mg]; ob = q; met = iou;
    }
    unsigned long long heavy = __ballot(count > 1);
    if (heavy){
      float4 pr = make_float4(0.f,0.f,0.f,0.f); int hv0 = 0;
      if (count > 1){
        pr = ((const float4*)priors)[n];
        hv0 = valid_mask[idx];
      }
      while (heavy){
        int src = (int)(__ffsll(heavy) - 1);
        heavy &= heavy - 1ull;
        float hx1 = __shfl(pb.x, src, 64), hy1 = __shfl(pb.y, src, 64);
        float hx2 = __shfl(pb.z, src, 64), hy2 = __shfl(pb.w, src, 64);
        float hpa = __shfl(pa,   src, 64);
        float hcx = __shfl(pr.x, src, 64), hcy = __shfl(pr.y, src, 64);
        float hst = __shfl(pr.z, src, 64);
        int   hv  = __shfl(hv0,  src, 64);
        int   hn  = __shfl(n,    src, 64);
        float hinvs = __uint_as_float(0x7F000000u - __float_as_uint(hst));
        const float* hrow = pred_scores + ((size_t)b*N_ + hn)*(size_t)NCLS;

        unsigned long long bk = ~0ull;
        #pragma unroll
        for (int h = 0; h < 2; ++h){
          int g = lane + h*64;
          if (g < G_){
            float4 q = sbox[g];
            float lx = fmaxf(hx1, q.x), ly = fmaxf(hy1, q.y);
            float rx = fminf(hx2, q.z), ry = fminf(hy2, q.w);
            float ov = fmaxf(rx - lx, 0.0f) * fmaxf(ry - ly, 0.0f);
            float un = hpa + sga[g] - ov;
            float iou = ov / fmaxf(un, 1e-6f);
            float dx = hcx - sgcx[g], dy = hcy - sgcy[g];
            float dist = sqrtf(dx*dx + dy*dy) * hinvs;
            float x = hrow[slbl[g]];
            float c = cost_eval(iou, x, dist, hv != 0);
            unsigned long long key = ((unsigned long long)fkey(c) << 32) | (unsigned)g;
            bk = key < bk ? key : bk;
          }
        }
        bk = wave_min_u64(bk);
        if (lane == src){
          int gw = (int)(bk & 0xffffffffu);
          float4 q = sbox[gw];
          float lx = fmaxf(pb.x, q.x), ly = fmaxf(pb.y, q.y);
          float rx = fminf(pb.z, q.z), ry = fminf(pb.w, q.w);
          float ov = fmaxf(rx - lx, 0.0f) * fmaxf(ry - ly, 0.0f);
          met  = ov / fmaxf(pa + sga[gw] - ov, 1e-6f);
          lblv = (float)slbl[gw];
          ob = q;
        }
      }
    }
  }

  out[idx] = lblv;                                   // assigned_labels
  out[(size_t)B_*N_ + idx] = 1.0f;                   // weights
  ((float4*)(out + (size_t)2*B_*N_))[idx] = ob;      // assigned_bboxes
  out[(size_t)6*B_*N_ + idx] = met;                  // assign_metrics
}

// ---------- launch ----------

extern "C" void kernel_launch(void* const* d_in, const int* in_sizes, int n_in,
                              void* d_out, int out_size, void* d_ws, size_t ws_size,
                              hipStream_t stream) {
  const float* pred_bboxes = (const float*)d_in[0];
  const float* pred_scores = (const float*)d_in[1];
  const float* priors      = (const float*)d_in[2];
  const int*   gt_labels   = (const int*)  d_in[3];
  const float* gt_bboxes   = (const float*)d_in[4];
  const float* pad_flag    = (const float*)d_in[5];
  float* out = (float*)d_out;

  // ws layout: match bitmask | valid mask | chunk keys | chunk ious | tile agg | tile flags
  const size_t MASK_B  = (size_t)B_*N_*4*sizeof(uint32_t);                        // 4,300,800
  const size_t VALID_B = ((size_t)B_*N_ + 255) & ~(size_t)255;                    //   268,800
  const size_t CK_B    = (size_t)B_*G_*NCHUNK*TOPK_*sizeof(unsigned long long);   //   166,400
  const size_t CI_B    = (size_t)B_*G_*NCHUNK*TOPK_*sizeof(float);                //    83,200
  const size_t AGG_B   = (size_t)B_*TILES*sizeof(float4);                         //    67,200
  uint32_t* match_mask = (uint32_t*)d_ws;
  unsigned char* valid_mask = (unsigned char*)d_ws + MASK_B;
  unsigned long long* ck = (unsigned long long*)((char*)d_ws + MASK_B + VALID_B);
  float* ci = (float*)((char*)d_ws + MASK_B + VALID_B + CK_B);
  float4* tile_agg = (float4*)((char*)d_ws + MASK_B + VALID_B + CK_B + CI_B);
  uint32_t* tile_flag = (uint32_t*)((char*)d_ws + MASK_B + VALID_B + CK_B + CI_B + AGG_B);

  dim3 gridN((N_ + BDIM - 1)/BDIM, B_);
  dim3 gridT(TILES, B_);
  dim3 gridG(G_, B_, NCHUNK);
  dim3 gridM(G_, B_);

  k_validmask<<<gridN, BDIM, 0, stream>>>(priors, gt_bboxes, pad_flag,
                                          valid_mask, match_mask);
  k_tileprep<<<gridT, 64, 0, stream>>>(pred_bboxes, valid_mask, tile_agg, tile_flag);
  k_topk<<<gridG, BDIM, 0, stream>>>(pred_bboxes, pred_scores, gt_labels,
                                     gt_bboxes, pad_flag, valid_mask,
                                     tile_agg, tile_flag, ck, ci);
  k_merge<<<gridM, 64, 0, stream>>>(pad_flag, ck, ci, match_mask);
  k_assign<<<gridN, BDIM, 0, stream>>>(pred_bboxes, pred_scores, priors, gt_labels,
                                       gt_bboxes, valid_mask, match_mask, out);
}

// Round 8
// 72.857 us; speedup vs baseline: 9.1593x; 1.0523x over previous
//
#include <hip/hip_runtime.h>
#include <stdint.h>

#define BDIM 256
#define TDIM 512           // k_topk block (8 waves)
#define B_   8
#define NCLS 80
#define G_   100
#define N_   33600
#define TOPK_ 13
#define TILES 525          // 400 (level0 20x20) + 100 (level1 10x10) + 25 (level2 5x5), 8x8 anchors each
#define NW   8             // waves per k_topk block
#define CAPC 160           // per-wave cost candidate buffer (u64 keys)
#define CAPI 160           // per-wave iou candidate buffer (f32)
#define INFC 1e8f

// ---------- helpers ----------

__device__ __forceinline__ unsigned int fkey(float f){
  unsigned int u = __float_as_uint(f);
  return (u & 0x80000000u) ? ~u : (u | 0x80000000u);  // monotonic float->uint
}
__device__ __forceinline__ float unfkey(unsigned int k){
  unsigned int u = (k & 0x80000000u) ? (k & 0x7fffffffu) : ~k;
  return __uint_as_float(u);
}

// cost = bce*(scale^2) + (-log(iou+eps)*3) + 10^(dist-3); INF-masked by valid
__device__ __forceinline__ float cost_eval(float iou, float x, float dist, bool valid){
  #pragma clang fp contract(off)
  float prior = exp2f((dist - 3.0f) * 3.321928094887362f);   // 10^(dist-3)
  float iouc  = -logf(iou + 1e-7f) * 3.0f;
  float sig   = 1.0f / (1.0f + expf(-x));
  float sc    = iou - sig;
  float bce   = fmaxf(x, 0.0f) + log1pf(expf(-fabsf(x))) - x * iou;
  float c     = bce * (sc * sc) + iouc + prior;
  return valid ? c : INFC;
}

__device__ __forceinline__ unsigned long long wave_min_u64(unsigned long long v){
  #pragma unroll
  for (int m = 1; m < 64; m <<= 1){
    unsigned int lo = (unsigned int)__shfl_xor((int)(unsigned int)v, m, 64);
    unsigned int hi = (unsigned int)__shfl_xor((int)(unsigned int)(v >> 32), m, 64);
    unsigned long long o = ((unsigned long long)hi << 32) | lo;
    v = o < v ? o : v;
  }
  return v;
}

// tile id -> level geometry. Tiles are 8x8 spatial patches; levels: 160x160(s=8), 80x80(s=16), 40x40(s=32).
__device__ __forceinline__ void tile_params(int t, int& W, int& base, int& trow, int& tcol,
                                            float& s, float& invs){
  if (t < 400){            W = 160; base = 0;     s = 8.0f;  invs = 0.125f;
    trow = (t/20)*8;  tcol = (t - (t/20)*20)*8; }
  else if (t < 500){ int u = t - 400; W = 80; base = 25600; s = 16.0f; invs = 0.0625f;
    trow = (u/10)*8; tcol = (u - (u/10)*10)*8; }
  else {             int u = t - 500; W = 40; base = 32000; s = 32.0f; invs = 0.03125f;
    trow = (u/5)*8;  tcol = (u - (u/5)*5)*8; }
}

// exact selection of 13 smallest u64 keys from buf[0..cnt) (cnt<=CAPC). keys unique.
__device__ unsigned long long compact_cost(unsigned long long* buf, int cnt){
  const int lane = threadIdx.x & 63;
  unsigned long long a0 = (lane       < cnt) ? buf[lane]       : ~0ull;
  unsigned long long a1 = (lane + 64  < cnt) ? buf[lane + 64]  : ~0ull;
  unsigned long long a2 = (lane + 128 < cnt) ? buf[lane + 128] : ~0ull;
  unsigned long long mykeep = ~0ull, t13 = ~0ull;
  #pragma unroll
  for (int r = 0; r < TOPK_; ++r){
    unsigned long long v = a0 < a1 ? a0 : a1; v = v < a2 ? v : a2;
    unsigned long long mn = wave_min_u64(v);
    if      (a0 == mn) a0 = ~0ull;
    else if (a1 == mn) a1 = ~0ull;
    else if (a2 == mn) a2 = ~0ull;
    if (lane == r) mykeep = mn;
    t13 = mn;
  }
  if (lane < TOPK_) buf[lane] = mykeep;
  return t13;
}

// exact selection of 13 largest floats (dups allowed) from buf[0..cnt).
__device__ float compact_iou(float* buf, int cnt){
  const int lane = threadIdx.x & 63;
  float a0 = (lane       < cnt) ? buf[lane]       : -1.0f;
  float a1 = (lane + 64  < cnt) ? buf[lane + 64]  : -1.0f;
  float a2 = (lane + 128 < cnt) ? buf[lane + 128] : -1.0f;
  float mykeep = -1.0f, t13 = -1.0f;
  #pragma unroll
  for (int r = 0; r < TOPK_; ++r){
    float mx = fmaxf(fmaxf(a0, a1), a2);
    #pragma unroll
    for (int m = 1; m < 64; m <<= 1) mx = fmaxf(mx, __shfl_xor(mx, m, 64));
    bool h0 = (a0 == mx), h1 = (a1 == mx), h2 = (a2 == mx);
    unsigned long long ball = __ballot(h0 | h1 | h2);
    int src = (int)(__ffsll(ball) - 1);
    if (lane == src){
      if (h0) a0 = -1.0f; else if (h1) a1 = -1.0f; else a2 = -1.0f;
    }
    if (lane == r) mykeep = mx;
    t13 = mx;
  }
  if (lane < TOPK_) buf[lane] = mykeep;
  return t13;
}

// ---------- kernel 0: fused per-tile prep: valid bits + zero bitmask + tile aggregates ----------

__global__ void __launch_bounds__(64) k_prep(
    const float* __restrict__ pred_bboxes,
    const float* __restrict__ gt_bboxes,
    const float* __restrict__ pad_flag,
    unsigned char* __restrict__ valid_mask,
    uint32_t* __restrict__ match_mask,
    float4* __restrict__ tile_agg,
    uint32_t* __restrict__ tile_flag)
{
  const int t = blockIdx.x, b = blockIdx.y, l = threadIdx.x;
  __shared__ float4 sbox[G_];
  __shared__ float  sflag[G_];
  for (int g = l; g < G_; g += 64){
    sbox[g]  = ((const float4*)gt_bboxes)[b*G_ + g];
    sflag[g] = pad_flag[b*G_ + g];
  }
  __syncthreads();

  int W, base, trow, tcol; float s, invs;
  tile_params(t, W, base, trow, tcol, s, invs);
  int row = trow + (l >> 3), col = tcol + (l & 7);
  int n = base + row*W + col;
  float cx = ((float)col + 0.5f)*s, cy = ((float)row + 0.5f)*s;   // == priors (exact)

  bool v = false;
  for (int g = 0; g < G_; ++g){
    float4 gb = sbox[g];
    bool in = (cx - gb.x > 0.0f) & (cy - gb.y > 0.0f) &
              (gb.z - cx > 0.0f) & (gb.w - cy > 0.0f) & (sflag[g] > 0.0f);
    v |= in;
  }
  size_t idx = (size_t)b*N_ + n;
  valid_mask[idx] = v ? 1 : 0;
  ((uint4*)match_mask)[idx] = make_uint4(0u,0u,0u,0u);

  float4 pb = ((const float4*)pred_bboxes)[idx];
  float x1 = pb.x, y1 = pb.y, x2 = pb.z, y2 = pb.w;
  #pragma unroll
  for (int m = 1; m < 64; m <<= 1){
    x1 = fminf(x1, __shfl_xor(x1, m, 64));
    y1 = fminf(y1, __shfl_xor(y1, m, 64));
    x2 = fmaxf(x2, __shfl_xor(x2, m, 64));
    y2 = fmaxf(y2, __shfl_xor(y2, m, 64));
  }
  unsigned long long anyb = __ballot(v);
  if (l == 0){
    tile_agg [(size_t)b*TILES + t] = make_float4(x1, y1, x2, y2);
    tile_flag[(size_t)b*TILES + t] = (anyb != 0ull) ? 1u : 0u;
  }
}

// ---------- kernel 1: per (b,g) tile-pruned top-13 + dyn_k + scatter (single block) ----------

__global__ void __launch_bounds__(TDIM) k_topk(
    const float* __restrict__ pred_bboxes,
    const float* __restrict__ pred_scores,
    const int*   __restrict__ gt_labels,
    const float* __restrict__ gt_bboxes,
    const float* __restrict__ pad_flag,
    const unsigned char* __restrict__ valid_mask,
    const float4* __restrict__ tile_agg,
    const uint32_t* __restrict__ tile_flag,
    uint32_t* __restrict__ match_mask)
{
  #pragma clang fp contract(off)
  const int g = blockIdx.x, b = blockIdx.y;
  if (pad_flag[b*G_ + g] <= 0.0f) return;   // invalid gt: no matches (uniform exit, pre-barrier)

  __shared__ unsigned long long s_cbuf[NW][CAPC];
  __shared__ float s_ibuf[NW][CAPI];
  __shared__ unsigned long long s_fk[NW*TOPK_];
  __shared__ float s_fi[NW*TOPK_];
  __shared__ float s_thr[2];

  const int tid = threadIdx.x, lane = tid & 63, wid = tid >> 6;
  unsigned long long* cbuf = s_cbuf[wid];
  float* ibuf = s_ibuf[wid];

  const float4 gb = ((const float4*)gt_bboxes)[b*G_ + g];
  const float ga  = (gb.z - gb.x) * (gb.w - gb.y);
  const float gcx = (gb.x + gb.z) * 0.5f, gcy = (gb.y + gb.w) * 0.5f;
  const int lbl = gt_labels[b*G_ + g];
  const unsigned int KEYINF = fkey(INFC);

  const float4* pb4 = (const float4*)pred_bboxes + (size_t)b*N_;
  const unsigned char* vm = valid_mask + (size_t)b*N_;
  const float* sc_b = pred_scores + (size_t)b*N_*NCLS;
  const float4* tag = tile_agg + (size_t)b*TILES;
  const uint32_t* tfl = tile_flag + (size_t)b*TILES;

  // ---- seed (wave 0 only, once per block): EXACT costs/ious of 75 patch anchors ----
  if (wid == 0){
    auto seed_eval = [&](int t, float& cst, float& iouv){
      #pragma clang fp contract(off)
      int nk, bs; float s, invs;
      if      (t < 25){ nk = 160; bs = 0;     s = 8.0f;  invs = 0.125f;   }
      else if (t < 50){ nk = 80;  bs = 25600; s = 16.0f; invs = 0.0625f;  }
      else            { nk = 40;  bs = 32000; s = 32.0f; invs = 0.03125f; }
      int rem = (t < 25) ? t : ((t < 50) ? t - 25 : t - 50);
      int r = rem / 5, c = rem - 5*r;
      int ix = (int)(gcx / s) - 2, iy = (int)(gcy / s) - 2;
      ix = ix < 0 ? 0 : (ix > nk-5 ? nk-5 : ix);
      iy = iy < 0 ? 0 : (iy > nk-5 ? nk-5 : iy);
      int col = ix + c, row = iy + r;
      int n = bs + row*nk + col;
      float4 pb = pb4[n];
      float pa = (pb.z - pb.x) * (pb.w - pb.y);
      float lx = fmaxf(pb.x, gb.x), ly = fmaxf(pb.y, gb.y);
      float rx = fminf(pb.z, gb.z), ry = fminf(pb.w, gb.w);
      float ov = fmaxf(rx - lx, 0.0f) * fmaxf(ry - ly, 0.0f);
      float un = pa + ga - ov;
      float iou = ov / fmaxf(un, 1e-6f);
      iouv = iou;
      bool valid = vm[n] != 0;
      float px = ((float)col + 0.5f)*s, py = ((float)row + 0.5f)*s;   // == priors (exact)
      float dx = px - gcx, dy = py - gcy;
      float dist = sqrtf(dx*dx + dy*dy) * invs;
      float x = valid ? sc_b[(size_t)n*NCLS + lbl] : 0.0f;
      cst = cost_eval(iou, x, dist, valid);
    };
    float c0 = 3e38f, c1 = 3e38f, i0 = -1.0f, i1 = -1.0f;
    seed_eval(lane, c0, i0);
    if (lane < 11) seed_eval(lane + 64, c1, i1);
    // probe thresholds: smallest cost level / largest iou level with >=13 seeds qualifying.
    float T = INFC;
    {
      const float lvs[7] = {47.0f, 24.0f, 12.0f, 6.0f, 3.0f, 1.5f, 0.75f};
      #pragma unroll
      for (int i = 0; i < 7; ++i){
        int cnt = __popcll(__ballot(c0 <= lvs[i])) + __popcll(__ballot(c1 <= lvs[i]));
        if (cnt >= TOPK_) T = lvs[i];
      }
    }
    float Ti = 0.0f;
    {
      const float ivs[8] = {0.02f, 0.05f, 0.1f, 0.15f, 0.22f, 0.3f, 0.4f, 0.5f};
      #pragma unroll
      for (int i = 0; i < 8; ++i){
        int cnt = __popcll(__ballot(i0 >= ivs[i])) + __popcll(__ballot(i1 >= ivs[i]));
        if (cnt >= TOPK_) Ti = ivs[i] * 0.999f;
      }
    }
    if (lane == 0){ s_thr[0] = T; s_thr[1] = Ti; }
  }
  __syncthreads();

  const float T0 = s_thr[0];
  float Tiou_m = s_thr[1];
  unsigned long long Tkey = ((unsigned long long)fkey(T0) << 32) | 0xFFFFFFFFull;
  bool  tc48  = T0 < 48.0f;
  float gt_   = 3.02f + log10f(T0);
  float gthr2 = gt_ * gt_;                // T0 >= 0.75 -> positive; T0=1e8 -> ~121 (cost>=prior bound)

  int ccnt = 0, icnt = 0;

  // ---- rare: bound is 1e8 -> invalid anchors (cost exactly 1e8, index tie-break) may rank.
  // All waves compute the identical sweep extent (dedup guard); wave 0 stores candidates.
  int sweep_nend = 0;
  if (T0 == INFC){
    int found = 0, base = 0;
    while (found < TOPK_ && base < N_){
      int n = base + lane;
      bool inv = (vm[n] == 0);
      unsigned long long m = __ballot(inv);
      int pc = __popcll(m);
      if (wid == 0){
        int pos = ccnt + (int)__popcll(m & ((1ull << lane) - 1ull));
        if (inv) cbuf[pos] = ((unsigned long long)KEYINF << 32) | (unsigned)n;
        ccnt += pc;                        // bounded: <=76 before first 13 found
      }
      found += pc;
      base += 64;
    }
    sweep_nend = base;                     // wave-uniform across ALL waves
  }

  // ---- tile loop: this wave's tile subrange ----
  const int per  = (TILES + NW - 1) / NW;  // 66
  const int lo_w = wid*per;
  const int hi_w = min(TILES, lo_w + per);

  for (int tb = lo_w; tb < hi_w; tb += 64){
    int tt2 = tb + lane;
    bool pass = false;
    if (tt2 < hi_w){
      float4 ag = tag[tt2];
      uint32_t fl2 = tfl[tt2];
      int W, bse, trow, tcol; float s, invs;
      tile_params(tt2, W, bse, trow, tcol, s, invs);
      bool inter = (fminf(ag.z, gb.z) > fmaxf(ag.x, gb.x)) &&
                   (fminf(ag.w, gb.w) > fmaxf(ag.y, gb.y));       // some anchor may have ov>0
      float rx0 = ((float)tcol + 0.5f)*s, rx1 = ((float)tcol + 7.5f)*s;
      float ry0 = ((float)trow + 0.5f)*s, ry1 = ((float)trow + 7.5f)*s;
      float ddx = fmaxf(0.0f, fmaxf(rx0 - gcx, gcx - rx1));        // <= per-anchor |dx| (FP-monotone)
      float ddy = fmaxf(0.0f, fmaxf(ry0 - gcy, gcy - ry1));
      float md2s = (ddx*ddx + ddy*ddy) * (invs*invs);
      bool costok = (fl2 != 0) && (md2s <= gthr2) && (inter || !tc48);
      pass = inter || costok;
    }
    unsigned long long pm = __ballot(pass);
    while (pm){
      int bit = (int)(__ffsll(pm) - 1);
      pm &= pm - 1ull;
      const int tt = tb + bit;                      // wave-uniform tile

      int W, bse, trow, tcol; float s, invs;
      tile_params(tt, W, bse, trow, tcol, s, invs);
      int row = trow + (lane >> 3), col = tcol + (lane & 7);
      int n = bse + row*W + col;
      float px = ((float)col + 0.5f)*s, py = ((float)row + 0.5f)*s;   // == priors (exact)
      float4 pb = pb4[n];
      float pa = (pb.z - pb.x) * (pb.w - pb.y);
      float lx = fmaxf(pb.x, gb.x), ly = fmaxf(pb.y, gb.y);
      float rx = fminf(pb.z, gb.z), ry = fminf(pb.w, gb.w);
      float ov = fmaxf(rx - lx, 0.0f) * fmaxf(ry - ly, 0.0f);
      float un = pa + ga - ov;
      bool ipass = ov > Tiou_m * un;

      float dx = px - gcx, dy = py - gcy;
      float dist2 = dx*dx + dy*dy;
      float d2s = dist2 * (invs * invs);
      bool valid = vm[n] != 0;
      bool needcost = valid && (d2s <= gthr2) && !((ov <= 0.0f) && tc48);

      float iou = 0.0f;
      if (__any(ipass || needcost)){
        if (ipass || needcost) iou = ov / fmaxf(un, 1e-6f);
      }

      // ---- iou top-13 stream ----
      {
        unsigned long long m = __ballot(ipass);
        if (m){
          int pc = __popcll(m);
          if (icnt + pc > CAPI){
            float t = compact_iou(ibuf, icnt); icnt = TOPK_;
            Tiou_m = t * 0.999f;
          }
          int pos = icnt + (int)__popcll(m & ((1ull << lane) - 1ull));
          if (ipass) ibuf[pos] = iou;
          icnt += pc;
        }
      }

      // ---- cost top-13 stream ----
      unsigned long long key = ((unsigned long long)KEYINF << 32) | (unsigned)n;
      bool cpass = (!valid) && (key < Tkey) && (n >= sweep_nend);
      if (__any(needcost)){
        if (needcost){
          float x = sc_b[(size_t)n*NCLS + lbl];
          float dist = sqrtf(dist2) * invs;
          float c = cost_eval(iou, x, dist, true);
          key = ((unsigned long long)fkey(c) << 32) | (unsigned)n;
          cpass = key < Tkey;
        }
      }
      {
        unsigned long long m = __ballot(cpass);
        if (m){
          int pc = __popcll(m);
          if (ccnt + pc > CAPC){
            Tkey = compact_cost(cbuf, ccnt); ccnt = TOPK_;
            float Tc = unfkey((unsigned int)(Tkey >> 32));
            tc48 = Tc < 48.0f;
            float gq = 3.02f + log10f(Tc);
            gthr2 = (gq > 0.0f) ? gq*gq : 1e30f;
          }
          int pos = ccnt + (int)__popcll(m & ((1ull << lane) - 1ull));
          if (cpass) cbuf[pos] = key;
          ccnt += pc;
        }
      }
    }
  }

  // ---- per-wave exact selection -> contiguous LDS lists ----
  compact_cost(cbuf, ccnt);
  compact_iou(ibuf, icnt);
  if (lane < TOPK_){ s_fk[wid*TOPK_ + lane] = cbuf[lane]; s_fi[wid*TOPK_ + lane] = ibuf[lane]; }
  __syncthreads();

  // ---- block-level exact selection over 8*13 entries (wave 0) ----
  if (wid == 0){
    compact_cost(s_fk, NW*TOPK_);   // ascending 13 smallest -> s_fk[0..13)
    compact_iou(s_fi, NW*TOPK_);    // descending 13 largest -> s_fi[0..13)
  }
  __syncthreads();

  if (tid == 0){
    float ssum = 0.0f;
    for (int r = 0; r < TOPK_; ++r) ssum += fmaxf(s_fi[r], 0.0f);   // descending order sum
    int dynk = (int)ssum;            // trunc toward zero
    if (dynk < 1) dynk = 1;
    if (dynk > TOPK_) dynk = TOPK_;
    for (int r = 0; r < dynk; ++r){
      int n = (int)(s_fk[r] & 0xffffffffu);
      if (n < N_)                    // insurance vs sentinel pick
        atomicOr(&match_mask[((size_t)b*N_ + n)*4 + (g >> 5)], 1u << (g & 31));
    }
  }
}

// ---------- kernel 2: per (b,n) final assignment ----------
// fast path count<=1; count>1 resolved wave-cooperatively (g across lanes)

__global__ void __launch_bounds__(BDIM) k_assign(
    const float* __restrict__ pred_bboxes,
    const float* __restrict__ pred_scores,
    const float* __restrict__ priors,
    const int*   __restrict__ gt_labels,
    const float* __restrict__ gt_bboxes,
    const unsigned char* __restrict__ valid_mask,
    const uint32_t* __restrict__ match_mask,
    float* __restrict__ out)
{
  #pragma clang fp contract(off)
  const int b = blockIdx.y;
  __shared__ float4 sbox[G_];
  __shared__ int    slbl[G_];
  __shared__ float  sga[G_], sgcx[G_], sgcy[G_];
  for (int g = threadIdx.x; g < G_; g += BDIM){
    float4 q = ((const float4*)gt_bboxes)[b*G_ + g];
    sbox[g] = q; slbl[g] = gt_labels[b*G_ + g];
    sga[g]  = (q.z - q.x) * (q.w - q.y);
    sgcx[g] = (q.x + q.z) * 0.5f;
    sgcy[g] = (q.y + q.w) * 0.5f;
  }
  __syncthreads();
  int n = blockIdx.x*BDIM + threadIdx.x;
  if (n >= N_) return;
  const int lane = threadIdx.x & 63;
  size_t idx = (size_t)b*N_ + n;
  uint4 mm = ((const uint4*)match_mask)[idx];
  int count = __popc(mm.x) + __popc(mm.y) + __popc(mm.z) + __popc(mm.w);

  float lblv = (float)NCLS;
  float4 ob = make_float4(0.f, 0.f, 0.f, 0.f);
  float met = 0.0f;

  if (__any(count > 0)){
    float4 pb = make_float4(0.f,0.f,0.f,0.f); float pa = 0.0f;
    if (count > 0){
      pb = ((const float4*)pred_bboxes)[idx];
      pa = (pb.z - pb.x) * (pb.w - pb.y);
    }
    if (count == 1){
      int mg = mm.x ? (__ffs(mm.x) - 1) :
               mm.y ? (31 + __ffs(mm.y)) :
               mm.z ? (63 + __ffs(mm.z)) : (95 + __ffs(mm.w));
      float4 q = sbox[mg];
      float lx = fmaxf(pb.x, q.x), ly = fmaxf(pb.y, q.y);
      float rx = fminf(pb.z, q.z), ry = fminf(pb.w, q.w);
      float ov = fmaxf(rx - lx, 0.0f) * fmaxf(ry - ly, 0.0f);
      float iou = ov / fmaxf(pa + sga[mg] - ov, 1e-6f);
      lblv = (float)slbl[mg]; ob = q; met = iou;
    }
    unsigned long long heavy = __ballot(count > 1);
    if (heavy){
      float4 pr = make_float4(0.f,0.f,0.f,0.f); int hv0 = 0;
      if (count > 1){
        pr = ((const float4*)priors)[n];
        hv0 = valid_mask[idx];
      }
      while (heavy){
        int src = (int)(__ffsll(heavy) - 1);
        heavy &= heavy - 1ull;
        float hx1 = __shfl(pb.x, src, 64), hy1 = __shfl(pb.y, src, 64);
        float hx2 = __shfl(pb.z, src, 64), hy2 = __shfl(pb.w, src, 64);
        float hpa = __shfl(pa,   src, 64);
        float hcx = __shfl(pr.x, src, 64), hcy = __shfl(pr.y, src, 64);
        float hst = __shfl(pr.z, src, 64);
        int   hv  = __shfl(hv0,  src, 64);
        int   hn  = __shfl(n,    src, 64);
        float hinvs = __uint_as_float(0x7F000000u - __float_as_uint(hst));
        const float* hrow = pred_scores + ((size_t)b*N_ + hn)*(size_t)NCLS;

        unsigned long long bk = ~0ull;
        #pragma unroll
        for (int h = 0; h < 2; ++h){
          int g = lane + h*64;
          if (g < G_){
            float4 q = sbox[g];
            float lx = fmaxf(hx1, q.x), ly = fmaxf(hy1, q.y);
            float rx = fminf(hx2, q.z), ry = fminf(hy2, q.w);
            float ov = fmaxf(rx - lx, 0.0f) * fmaxf(ry - ly, 0.0f);
            float un = hpa + sga[g] - ov;
            float iou = ov / fmaxf(un, 1e-6f);
            float dx = hcx - sgcx[g], dy = hcy - sgcy[g];
            float dist = sqrtf(dx*dx + dy*dy) * hinvs;
            float x = hrow[slbl[g]];
            float c = cost_eval(iou, x, dist, hv != 0);
            unsigned long long key = ((unsigned long long)fkey(c) << 32) | (unsigned)g;
            bk = key < bk ? key : bk;
          }
        }
        bk = wave_min_u64(bk);
        if (lane == src){
          int gw = (int)(bk & 0xffffffffu);
          float4 q = sbox[gw];
          float lx = fmaxf(pb.x, q.x), ly = fmaxf(pb.y, q.y);
          float rx = fminf(pb.z, q.z), ry = fminf(pb.w, q.w);
          float ov = fmaxf(rx - lx, 0.0f) * fmaxf(ry - ly, 0.0f);
          met  = ov / fmaxf(pa + sga[gw] - ov, 1e-6f);
          lblv = (float)slbl[gw];
          ob = q;
        }
      }
    }
  }

  out[idx] = lblv;                                   // assigned_labels
  out[(size_t)B_*N_ + idx] = 1.0f;                   // weights
  ((float4*)(out + (size_t)2*B_*N_))[idx] = ob;      // assigned_bboxes
  out[(size_t)6*B_*N_ + idx] = met;                  // assign_metrics
}

// ---------- launch ----------

extern "C" void kernel_launch(void* const* d_in, const int* in_sizes, int n_in,
                              void* d_out, int out_size, void* d_ws, size_t ws_size,
                              hipStream_t stream) {
  const float* pred_bboxes = (const float*)d_in[0];
  const float* pred_scores = (const float*)d_in[1];
  const float* priors      = (const float*)d_in[2];
  const int*   gt_labels   = (const int*)  d_in[3];
  const float* gt_bboxes   = (const float*)d_in[4];
  const float* pad_flag    = (const float*)d_in[5];
  float* out = (float*)d_out;

  // ws layout: match bitmask | valid mask | tile agg | tile flags
  const size_t MASK_B  = (size_t)B_*N_*4*sizeof(uint32_t);                        // 4,300,800
  const size_t VALID_B = ((size_t)B_*N_ + 255) & ~(size_t)255;                    //   268,800
  const size_t AGG_B   = (size_t)B_*TILES*sizeof(float4);                         //    67,200
  uint32_t* match_mask = (uint32_t*)d_ws;
  unsigned char* valid_mask = (unsigned char*)d_ws + MASK_B;
  float4* tile_agg = (float4*)((char*)d_ws + MASK_B + VALID_B);
  uint32_t* tile_flag = (uint32_t*)((char*)d_ws + MASK_B + VALID_B + AGG_B);

  dim3 gridT(TILES, B_);
  dim3 gridG(G_, B_);
  dim3 gridN((N_ + BDIM - 1)/BDIM, B_);

  k_prep<<<gridT, 64, 0, stream>>>(pred_bboxes, gt_bboxes, pad_flag,
                                   valid_mask, match_mask, tile_agg, tile_flag);
  k_topk<<<gridG, TDIM, 0, stream>>>(pred_bboxes, pred_scores, gt_labels,
                                     gt_bboxes, pad_flag, valid_mask,
                                     tile_agg, tile_flag, match_mask);
  k_assign<<<gridN, BDIM, 0, stream>>>(pred_bboxes, pred_scores, priors, gt_labels,
                                       gt_bboxes, valid_mask, match_mask, out);
}